// Round 11
// baseline (312.953 us; speedup 1.0000x reference)
//
#include <hip/hip_runtime.h>
#include <hip/hip_bf16.h>
#include <cstdint>
#include <cstddef>

typedef __bf16 bf16_t;
typedef __bf16 bf16x4 __attribute__((ext_vector_type(4)));
typedef __bf16 bf16x8 __attribute__((ext_vector_type(8)));
typedef float f32x4 __attribute__((ext_vector_type(4)));

#define DEVINL __device__ __forceinline__

// B=2, T=2048, D=1024, H=16, d=64, I=2816
#define TT 2048
#define DD 1024
#define HH 16
#define II 2816

DEVINL float waveSum(float v) {
#pragma unroll
  for (int m = 32; m >= 1; m >>= 1) v += __shfl_xor(v, m, 64);
  return v;
}

DEVINL float sigmoidf_(float z) { return 1.0f / (1.0f + __expf(-z)); }

DEVINL void gload_lds16(const bf16_t* g, bf16_t* l) {
  __builtin_amdgcn_global_load_lds((const __attribute__((address_space(1))) void*)g,
                                   (__attribute__((address_space(3))) void*)l, 16, 0, 0);
}

// ---------------- fused weight prep: cvt 5x DxD, pack GU interleaved, cvt down, zero stats ----
__global__ __launch_bounds__(256) void prep_kernel(const float* __restrict__ Wq,
                                                   const float* __restrict__ Wk,
                                                   const float* __restrict__ Wv,
                                                   const float* __restrict__ Wg,
                                                   const float* __restrict__ Wo,
                                                   const float* __restrict__ gate_w,
                                                   const float* __restrict__ up_w,
                                                   const float* __restrict__ down_w,
                                                   bf16_t* __restrict__ Wqkvg_bf,
                                                   bf16_t* __restrict__ Wo_bf,
                                                   bf16_t* __restrict__ GU_bf,
                                                   bf16_t* __restrict__ down_bf,
                                                   float* __restrict__ stats) {
  const int bid = blockIdx.x;
  const int tid = threadIdx.x;
  if (bid == 0 && tid < 64) stats[tid] = 0.f;
  if (bid < 5120) {
    const int which = bid >> 10;
    const float* src;
    bf16_t* dst;
    switch (which) {
      case 0: src = Wq; dst = Wqkvg_bf; break;
      case 1: src = Wk; dst = Wqkvg_bf + (size_t)DD * DD; break;
      case 2: src = Wv; dst = Wqkvg_bf + 2 * (size_t)DD * DD; break;
      case 3: src = Wg; dst = Wqkvg_bf + 3 * (size_t)DD * DD; break;
      default: src = Wo; dst = Wo_bf; break;
    }
    const int i = (bid & 1023) * 256 + tid;
    float4 v = reinterpret_cast<const float4*>(src)[i];
    bf16x4 o;
    o[0] = (bf16_t)v.x; o[1] = (bf16_t)v.y; o[2] = (bf16_t)v.z; o[3] = (bf16_t)v.w;
    reinterpret_cast<bf16x4*>(dst)[i] = o;
  } else if (bid < 10752) {
    // GU pack: dst row r: jb=r/32, s=r%32; s<16 -> gate row 16*jb+s ; else up
    const int r = bid - 5120;
    const int jb = r >> 5, s = r & 31;
    const float* src = (s < 16) ? (gate_w + (size_t)(jb * 16 + s) * DD)
                                : (up_w + (size_t)(jb * 16 + s - 16) * DD);
    float4 v = reinterpret_cast<const float4*>(src)[tid];
    bf16x4 o;
    o[0] = (bf16_t)v.x; o[1] = (bf16_t)v.y; o[2] = (bf16_t)v.z; o[3] = (bf16_t)v.w;
    reinterpret_cast<bf16x4*>(GU_bf + (size_t)r * DD)[tid] = o;
  } else {
    const int i = (bid - 10752) * 256 + tid;
    float4 v = reinterpret_cast<const float4*>(down_w)[i];
    bf16x4 o;
    o[0] = (bf16_t)v.x; o[1] = (bf16_t)v.y; o[2] = (bf16_t)v.z; o[3] = (bf16_t)v.w;
    reinterpret_cast<bf16x4*>(down_bf)[i] = o;
  }
}

// ---------------- f32 copy (split-K epilogue init: C = src) ----------------
__global__ __launch_bounds__(256) void copy_f32_kernel(const float* __restrict__ src,
                                                       float* __restrict__ dst, int n4) {
  for (int i = blockIdx.x * 256 + threadIdx.x; i < n4; i += gridDim.x * 256)
    reinterpret_cast<float4*>(dst)[i] = reinterpret_cast<const float4*>(src)[i];
}

// ---------------- RMSNorm (row of 1024) -> bf16 ----------------
__global__ __launch_bounds__(256) void rmsnorm_kernel(const float* __restrict__ x,
                                                      const float* __restrict__ w,
                                                      bf16_t* __restrict__ out) {
  const int row = blockIdx.x;
  const int tid = threadIdx.x;
  const float4 v = reinterpret_cast<const float4*>(x + (size_t)row * DD)[tid];
  float ss = v.x * v.x + v.y * v.y + v.z * v.z + v.w * v.w;
  ss = waveSum(ss);
  __shared__ float red[4];
  if ((tid & 63) == 0) red[tid >> 6] = ss;
  __syncthreads();
  const float total = red[0] + red[1] + red[2] + red[3];
  const float rstd = rsqrtf(total * (1.0f / (float)DD) + 1e-6f);
  const float4 wv = reinterpret_cast<const float4*>(w)[tid];
  bf16x4 o;
  o[0] = (bf16_t)(v.x * rstd * wv.x);
  o[1] = (bf16_t)(v.y * rstd * wv.y);
  o[2] = (bf16_t)(v.z * rstd * wv.z);
  o[3] = (bf16_t)(v.w * rstd * wv.w);
  reinterpret_cast<bf16x4*>(out + (size_t)row * DD)[tid] = o;
}

// ============ 128x256 8-wave BK=32 ring-3 GEMM (B^T input), 2 blocks/CU ============
// C[m,n] = sum_k A[m,k]*B[n,k].  M%128==0, N%256==0, K%32==0, K>=96.
// EPI: 2 = silu-fused bf16 (gate/up interleaved pairs, out stride II)
//      3 = qkv/g split bf16 (col<3072 -> O1 stride 3072; else sigmoid -> O2 stride DD)
template <int EPI>
__global__ __launch_bounds__(512, 4) void gemm128x256(const bf16_t* __restrict__ A,
                                                      const bf16_t* __restrict__ B,
                                                      bf16_t* __restrict__ O1,
                                                      bf16_t* __restrict__ O2,
                                                      int M, int N, int K) {
  extern __shared__ __align__(16) char lds[];
  const int tid = threadIdx.x;
  const int wid = tid >> 6;   // 0..7
  const int lane = tid & 63;
  const int wr = wid >> 2;    // 0..1  M-halves of 64
  const int wc = wid & 3;     // 0..3  N-quarters of 64

  // XCD-aware swizzle of flat block id (nwg % 8 == 0 for our grids: 512, 704)
  const int gx = gridDim.x;
  const int nwg = gx * gridDim.y;
  int flat = blockIdx.y * gx + blockIdx.x;
  flat = (flat & 7) * (nwg >> 3) + (flat >> 3);
  const int row0 = (flat / gx) * 128;
  const int col0 = (flat % gx) * 256;

  const int ls_row = lane >> 2;
  const int ls_col = ((lane & 3) ^ ((lane >> 3) & 3)) * 8;
  const bf16_t* gA = A + (size_t)(row0 + wid * 16 + ls_row) * K + ls_col;
  const bf16_t* gB = B + (size_t)(col0 + wid * 32 + ls_row) * K + ls_col;

  const int kq = lane >> 4;
  const int rl = lane & 15;
  const int xg = (rl >> 1) & 3;
  const int gsel = (kq ^ xg) << 4;  // byte offset of the lane's 16B granule

  f32x4 acc[4][4] = {};
  const int nt = K >> 5;  // >= 3

  auto stage = [&](int t) {
    char* slot = lds + (t % 3) * 24576;
    const int ko = t << 5;
    gload_lds16(gA + ko, (bf16_t*)(slot + wid * 1024));               // A: 128x32
#pragma unroll
    for (int j = 0; j < 2; ++j)                                       // B: 256x32
      gload_lds16(gB + (size_t)j * 16 * K + ko,
                  (bf16_t*)(slot + 8192 + wid * 2048 + j * 1024));
  };

  // prologue: stage tiles 0,1 ; wait tile 0 (3 = tile 1 remains in flight)
  stage(0); stage(1);
  asm volatile("s_waitcnt vmcnt(3)" ::: "memory");
  __builtin_amdgcn_s_barrier();
  __builtin_amdgcn_sched_barrier(0);

  for (int t = 0; t < nt; ++t) {
    if (t + 2 < nt) stage(t + 2);  // slot (t+2)%3 == (t-1)%3, read finished at t-1 barrier
    const char* ab = lds + (t % 3) * 24576;
    const char* bb = ab + 8192;
    bf16x8 aF[4], bF[4];
#pragma unroll
    for (int n = 0; n < 4; ++n)
      bF[n] = *reinterpret_cast<const bf16x8*>(bb + (wc * 64 + n * 16 + rl) * 64 + gsel);
#pragma unroll
    for (int m = 0; m < 4; ++m)
      aF[m] = *reinterpret_cast<const bf16x8*>(ab + (wr * 64 + m * 16 + rl) * 64 + gsel);
    __builtin_amdgcn_s_setprio(1);
#pragma unroll
    for (int m = 0; m < 4; ++m)
#pragma unroll
      for (int n = 0; n < 4; ++n)
        acc[m][n] = __builtin_amdgcn_mfma_f32_16x16x32_bf16(aF[m], bF[n], acc[m][n], 0, 0, 0);
    __builtin_amdgcn_s_setprio(0);
    if (t + 2 < nt) {
      asm volatile("s_waitcnt vmcnt(3)" ::: "memory");
    } else if (t + 2 == nt) {
      asm volatile("s_waitcnt vmcnt(0)" ::: "memory");
    }
    __builtin_amdgcn_s_barrier();
    __builtin_amdgcn_sched_barrier(0);
  }

  // ---- epilogue ----
  const int crow = row0 + wr * 64 + kq * 4;
  const int ccol = col0 + wc * 64 + rl;
  if (EPI == 2) {
    const int obase = (col0 + wc * 64) / 2 + rl;
#pragma unroll
    for (int m = 0; m < 4; ++m)
#pragma unroll
      for (int p = 0; p < 2; ++p)
#pragma unroll
        for (int r = 0; r < 4; ++r) {
          const float g = acc[m][2 * p][r];
          const float u = acc[m][2 * p + 1][r];
          O1[(size_t)(crow + m * 16 + r) * II + (obase + p * 16)] =
              (bf16_t)(g * sigmoidf_(g) * u);
        }
  } else {  // EPI == 3
    if (col0 < 3072) {
#pragma unroll
      for (int m = 0; m < 4; ++m)
#pragma unroll
        for (int n = 0; n < 4; ++n)
#pragma unroll
          for (int r = 0; r < 4; ++r)
            O1[(size_t)(crow + m * 16 + r) * 3072 + (ccol + n * 16)] = (bf16_t)acc[m][n][r];
    } else {
#pragma unroll
      for (int m = 0; m < 4; ++m)
#pragma unroll
        for (int n = 0; n < 4; ++n)
#pragma unroll
          for (int r = 0; r < 4; ++r)
            O2[(size_t)(crow + m * 16 + r) * DD + (ccol + n * 16 - 3072)] =
                (bf16_t)sigmoidf_(acc[m][n][r]);
    }
  }
}

// -------- 128x128 4-wave split-K GEMM (N=1024: Wo, down), C += acc via atomics --------
// blockIdx.z = K-split. C must be pre-initialized with the residual (copy_f32_kernel).
// Grid M/128 x N/128 x SPLIT = 1024 blocks -> 4 blocks/CU (m97 overlap regime).
__global__ __launch_bounds__(256) void gemm_bt_sk(const bf16_t* __restrict__ A,
                                                  const bf16_t* __restrict__ B,
                                                  float* __restrict__ C,
                                                  int M, int N, int K, int Ksub) {
  __shared__ __align__(16) bf16_t smA[128 * 32];
  __shared__ __align__(16) bf16_t smB[128 * 32];
  const int tid = threadIdx.x;
  const int wid = tid >> 6;
  const int lane = tid & 63;
  const int row0 = blockIdx.y * 128;
  const int col0 = blockIdx.x * 128;
  const int kbase = blockIdx.z * Ksub;
  const int wr = wid >> 1, wc = wid & 1;

  f32x4 acc[4][4] = {};

  const int sr = (wid * 2) * 16 + (lane >> 2);
  const int sc = (((lane & 3) ^ ((lane >> 3) & 3))) * 8;  // inverse-swizzled source
  const bf16_t* gA = A + (size_t)(row0 + sr) * K + kbase + sc;
  const bf16_t* gB = B + (size_t)(col0 + sr) * K + kbase + sc;
  bf16_t* lA = smA + wid * 1024;
  bf16_t* lB = smB + wid * 1024;

  const int rl = lane & 15;
  const int kq = lane >> 4;
  const int xg = (rl >> 1) & 3;
  const int ge = (kq ^ xg) * 8;  // element offset of the lane's granule
  const int aoff = (wr * 64 + rl) * 32 + ge;
  const int boff = (wc * 64 + rl) * 32 + ge;

  for (int k0 = 0; k0 < Ksub; k0 += 32) {
#pragma unroll
    for (int j2 = 0; j2 < 2; ++j2) {
      gload_lds16(gA + (size_t)j2 * 16 * K + k0, lA + j2 * 512);
      gload_lds16(gB + (size_t)j2 * 16 * K + k0, lB + j2 * 512);
    }
    __syncthreads();
    bf16x8 aF[4], bF[4];
#pragma unroll
    for (int m = 0; m < 4; ++m)
      aF[m] = *reinterpret_cast<const bf16x8*>(smA + aoff + m * 16 * 32);
#pragma unroll
    for (int n = 0; n < 4; ++n)
      bF[n] = *reinterpret_cast<const bf16x8*>(smB + boff + n * 16 * 32);
#pragma unroll
    for (int m = 0; m < 4; ++m)
#pragma unroll
      for (int n = 0; n < 4; ++n)
        acc[m][n] = __builtin_amdgcn_mfma_f32_16x16x32_bf16(aF[m], bF[n], acc[m][n], 0, 0, 0);
    __syncthreads();
  }

  const int crow = row0 + wr * 64 + kq * 4;
  const int ccol = col0 + wc * 64 + rl;
#pragma unroll
  for (int m = 0; m < 4; ++m)
#pragma unroll
    for (int n = 0; n < 4; ++n)
#pragma unroll
      for (int r = 0; r < 4; ++r) {
        const size_t idx = (size_t)(crow + m * 16 + r) * N + (ccol + n * 16);
        atomicAdd(&C[idx], acc[m][n][r]);
      }
}

// ---------------- RetNet windowed decay scan on MFMA + fused GN partial stats ----------------
__global__ __launch_bounds__(256) void retscan_mfma(const bf16_t* __restrict__ qkv,
                                                    const float* __restrict__ gamma,
                                                    float* __restrict__ y,
                                                    float* __restrict__ stats) {
  const int c = blockIdx.x;
  const int bh = blockIdx.y;
  const int b = bh >> 4;
  const int h = bh & 15;
  const int tid = threadIdx.x;
  const int w = tid >> 6;
  const int lane = tid & 63;
  const int kq = lane >> 4;
  const int rl = lane & 15;

  __shared__ __align__(16) bf16_t K_lds[128 * 64];    // [sw][j]   swizzled
  __shared__ __align__(16) bf16_t VT_lds[64 * 128];   // [e][sw]   swizzled
  __shared__ __align__(16) bf16_t P_lds[64 * 128];    // [i][sw]   swizzled
  __shared__ float rs[4][2];

  const size_t rstr = 3 * DD;
  const bf16_t* base = qkv + (size_t)(b * TT) * rstr + h * 64;  // Q
  const bf16_t* kgl = base + DD;
  const bf16_t* vgl = base + 2 * DD;

  // ---- stage K (swizzled) and V^T (transposed, swizzled) ----
  for (int g = tid; g < 1024; g += 256) {
    const int sw = g >> 3, gr = g & 7;
    const int t = c * 64 - 64 + sw;
    bf16x8 kv = {};
    bf16x8 vv = {};
    if (t >= 0) {
      kv = *reinterpret_cast<const bf16x8*>(kgl + (size_t)t * rstr + gr * 8);
      vv = *reinterpret_cast<const bf16x8*>(vgl + (size_t)t * rstr + gr * 8);
    }
    *reinterpret_cast<bf16x8*>(K_lds + sw * 64 + ((gr ^ (sw & 7)) << 3)) = kv;
#pragma unroll
    for (int j = 0; j < 8; ++j) {
      const int e = gr * 8 + j;
      const int gs = (sw >> 3) ^ (e & 7);
      VT_lds[e * 128 + (gs << 3) + (sw & 7)] = vv[j];
    }
  }

  // ---- Q fragments (direct from global; rows i0..i0+15 of this wave) ----
  const int i0 = w * 16;
  const bf16_t* qrow = base + (size_t)(c * 64 + i0 + rl) * rstr;
  bf16x8 qF0 = *reinterpret_cast<const bf16x8*>(qrow + kq * 8);
  bf16x8 qF1 = *reinterpret_cast<const bf16x8*>(qrow + 32 + kq * 8);
  const float gam = sigmoidf_(gamma[h]);
  const float l2g = __log2f(gam);
  const float gi16 = exp2f(-16.f * l2g);  // gam^-16: lag decreases by 16 per sw-tile

  __syncthreads();

  // ---- QK^T: S[i=i0+kq*4+r][sw=st*16+rl] ----
  f32x4 S[8];
#pragma unroll
  for (int st = 0; st < 8; ++st) {
    const int sw = st * 16 + rl;
    const bf16_t* krow = K_lds + sw * 64;
    bf16x8 kF0 = *reinterpret_cast<const bf16x8*>(krow + ((kq ^ (sw & 7)) << 3));
    bf16x8 kF1 = *reinterpret_cast<const bf16x8*>(krow + (((4 + kq) ^ (sw & 7)) << 3));
    f32x4 s = {};
    s = __builtin_amdgcn_mfma_f32_16x16x32_bf16(qF0, kF0, s, 0, 0, 0);
    s = __builtin_amdgcn_mfma_f32_16x16x32_bf16(qF1, kF1, s, 0, 0, 0);
    S[st] = s;
  }

  // ---- decay * mask -> bf16 P (own rows only) ----
  float wgt[4];
  int lag[4];
#pragma unroll
  for (int r = 0; r < 4; ++r) {
    lag[r] = 64 + i0 + kq * 4 + r - rl;  // at st=0; always >=0 here
    wgt[r] = exp2f((float)lag[r] * l2g);
  }
#pragma unroll
  for (int st = 0; st < 8; ++st) {
    const int sw = st * 16 + rl;
#pragma unroll
    for (int r = 0; r < 4; ++r) {
      const float p = (lag[r] >= 0) ? S[st][r] * wgt[r] : 0.f;
      const int i = i0 + kq * 4 + r;
      const int gs = (sw >> 3) ^ (i & 7);
      P_lds[i * 128 + (gs << 3) + (sw & 7)] = (bf16_t)p;
      lag[r] -= 16;
      wgt[r] *= gi16;
    }
  }
  asm volatile("s_waitcnt lgkmcnt(0)" ::: "memory");
  __builtin_amdgcn_sched_barrier(0);

  // ---- PV: Y[i][e] = sum_sw P[i][sw] * V[sw][e] ----
  f32x4 Y[4] = {};
#pragma unroll
  for (int ks = 0; ks < 4; ++ks) {
    const int ia = i0 + rl;
    const int ga = (ks * 4 + kq) ^ (ia & 7);
    bf16x8 aF = *reinterpret_cast<const bf16x8*>(P_lds + ia * 128 + (ga << 3));
#pragma unroll
    for (int et = 0; et < 4; ++et) {
      const int e = et * 16 + rl;
      const int gb = (ks * 4 + kq) ^ (e & 7);
      bf16x8 bF = *reinterpret_cast<const bf16x8*>(VT_lds + e * 128 + (gb << 3));
      Y[et] = __builtin_amdgcn_mfma_f32_16x16x32_bf16(aF, bF, Y[et], 0, 0, 0);
    }
  }

  // ---- store y (f32) + fused GN partial stats ----
  float s = 0.f, ss = 0.f;
  const size_t ybase = (size_t)(b * TT + c * 64 + i0 + kq * 4) * DD + h * 64 + rl;
#pragma unroll
  for (int et = 0; et < 4; ++et)
#pragma unroll
    for (int r = 0; r < 4; ++r) {
      const float v = Y[et][r];
      s += v;
      ss += v * v;
      y[ybase + (size_t)r * DD + et * 16] = v;
    }
  s = waveSum(s);
  ss = waveSum(ss);
  if (lane == 0) { rs[w][0] = s; rs[w][1] = ss; }
  __syncthreads();
  if (tid == 0) {
    atomicAdd(&stats[bh * 2], rs[0][0] + rs[1][0] + rs[2][0] + rs[3][0]);
    atomicAdd(&stats[bh * 2 + 1], rs[0][1] + rs[1][1] + rs[2][1] + rs[3][1]);
  }
}

// ---------------- GroupNorm apply (finalize stats) * pre-sigmoided gate -> bf16 ----------------
__global__ __launch_bounds__(256) void gn_apply_kernel(const float* __restrict__ y,
                                                       const float* __restrict__ stats,
                                                       const bf16_t* __restrict__ gsig,
                                                       const float* __restrict__ gn_w,
                                                       const float* __restrict__ gn_b,
                                                       bf16_t* __restrict__ out) {
  const int row = blockIdx.x;
  const int tid = threadIdx.x;
  const int col = tid * 4;
  const int b = row >> 11;
  const int h = col >> 6;
  const float S = stats[(b * HH + h) * 2];
  const float SS = stats[(b * HH + h) * 2 + 1];
  const float inv = 1.0f / ((float)TT * 64.0f);
  const float mean = S * inv;
  const float var = SS * inv - mean * mean;
  const float rstd = rsqrtf(var + 1e-5f);
  float4 v = reinterpret_cast<const float4*>(y + (size_t)row * DD)[tid];
  float4 wv = reinterpret_cast<const float4*>(gn_w)[tid];
  float4 bv = reinterpret_cast<const float4*>(gn_b)[tid];
  bf16x4 gv = reinterpret_cast<const bf16x4*>(gsig + (size_t)row * DD)[tid];
  bf16x4 o;
  o[0] = (bf16_t)((((v.x - mean) * rstd) * wv.x + bv.x) * (float)gv[0]);
  o[1] = (bf16_t)((((v.y - mean) * rstd) * wv.y + bv.y) * (float)gv[1]);
  o[2] = (bf16_t)((((v.z - mean) * rstd) * wv.z + bv.z) * (float)gv[2]);
  o[3] = (bf16_t)((((v.w - mean) * rstd) * wv.w + bv.w) * (float)gv[3]);
  reinterpret_cast<bf16x4*>(out + (size_t)row * DD)[tid] = o;
}

extern "C" void kernel_launch(void* const* d_in, const int* in_sizes, int n_in,
                              void* d_out, int out_size, void* d_ws, size_t ws_size,
                              hipStream_t stream) {
  const float* x = (const float*)d_in[0];
  const float* ln1_w = (const float*)d_in[1];
  const float* ln2_w = (const float*)d_in[2];
  const float* Wq = (const float*)d_in[3];
  const float* Wk = (const float*)d_in[4];
  const float* Wv = (const float*)d_in[5];
  const float* Wg = (const float*)d_in[6];
  const float* Wo = (const float*)d_in[7];
  const float* gamma = (const float*)d_in[8];
  const float* gn_w = (const float*)d_in[9];
  const float* gn_b = (const float*)d_in[10];
  const float* gate_w = (const float*)d_in[11];
  const float* up_w = (const float*)d_in[12];
  const float* down_w = (const float*)d_in[13];
  float* out = (float*)d_out;

  const int M = 2 * TT;  // 4096

  char* ws = (char*)d_ws;
  size_t off = 0;
  auto alloc = [&](size_t bytes) -> void* {
    void* p = ws + off;
    off += (bytes + 255) & ~(size_t)255;
    return p;
  };
  bf16_t* h_bf = (bf16_t*)alloc((size_t)M * DD * 2);
  bf16_t* Wqkvg_bf = (bf16_t*)alloc((size_t)4 * DD * DD * 2);
  bf16_t* Wo_bf = (bf16_t*)alloc((size_t)DD * DD * 2);
  bf16_t* GU_bf = (bf16_t*)alloc((size_t)2 * II * DD * 2);
  bf16_t* down_bf = (bf16_t*)alloc((size_t)DD * II * 2);
  bf16_t* qkv_bf = (bf16_t*)alloc((size_t)M * 3 * DD * 2);
  bf16_t* gsig = (bf16_t*)alloc((size_t)M * DD * 2);
  float* yBuf = (float*)alloc((size_t)M * DD * 4);
  bf16_t* ygated = (bf16_t*)alloc((size_t)M * DD * 2);
  bf16_t* act = (bf16_t*)alloc((size_t)M * II * 2);
  float* stats = (float*)alloc(64 * 4);
  (void)ws_size; (void)in_sizes; (void)n_in; (void)out_size;

  float* x2 = yBuf;
  const int n4_MD = M * DD / 4;

  // fused weight prep (+ stats zeroing)
  prep_kernel<<<13568, 256, 0, stream>>>(Wq, Wk, Wv, Wg, Wo, gate_w, up_w, down_w,
                                         Wqkvg_bf, Wo_bf, GU_bf, down_bf, stats);

  // h = rmsnorm(x) -> bf16
  rmsnorm_kernel<<<M, 256, 0, stream>>>(x, ln1_w, h_bf);

  // qkv (bf16) + sigmoid(g) (bf16) = h @ [Wq;Wk;Wv;Wg]^T
  {
    dim3 g(4 * DD / 256, M / 128);  // 16 x 32 = 512 blocks = 2/CU
    gemm128x256<3><<<g, 512, 73728, stream>>>(h_bf, Wqkvg_bf, qkv_bf, gsig, M, 4 * DD, DD);
  }

  // windowed decay scan (MFMA) -> y (f32) + partial GN stats
  {
    dim3 g(TT / 64, 2 * HH);
    retscan_mfma<<<g, 256, 0, stream>>>(qkv_bf, gamma, yBuf, stats);
  }

  // GN apply * sigmoid(g)
  gn_apply_kernel<<<M, 256, 0, stream>>>(yBuf, stats, gsig, gn_w, gn_b, ygated);

  // x2 = x + ygated @ Wo^T : init x2 = x, then split-K atomic accumulate
  // (gn_apply above has finished reading yBuf before this copy overwrites it)
  copy_f32_kernel<<<2048, 256, 0, stream>>>(x, x2, n4_MD);
  {
    dim3 g(DD / 128, M / 128, 4);  // 8 x 32 x 4 = 1024 blocks = 4/CU, Ksub=256
    gemm_bt_sk<<<g, 256, 0, stream>>>(ygated, Wo_bf, x2, M, DD, DD, DD / 4);
  }

  // h2 = rmsnorm(x2) -> bf16
  rmsnorm_kernel<<<M, 256, 0, stream>>>(x2, ln2_w, h_bf);

  // act = silu(h2 @ gate^T) * (h2 @ up^T) -> bf16, fused epilogue
  {
    dim3 g(2 * II / 256, M / 128);  // 22 x 32 = 704 blocks
    gemm128x256<2><<<g, 512, 73728, stream>>>(h_bf, GU_bf, act, nullptr, M, 2 * II, DD);
  }

  // out = x2 + act @ down^T : init out = x2, then split-K atomic accumulate
  copy_f32_kernel<<<2048, 256, 0, stream>>>(x2, out, n4_MD);
  {
    dim3 g(DD / 128, M / 128, 4);  // 1024 blocks = 4/CU, Ksub=704
    gemm_bt_sk<<<g, 256, 0, stream>>>(act, down_bf, out, M, DD, II, II / 4);
  }
}

// Round 12
// 246.949 us; speedup vs baseline: 1.2673x; 1.2673x over previous
//
#include <hip/hip_runtime.h>
#include <hip/hip_bf16.h>
#include <cstdint>
#include <cstddef>

typedef __bf16 bf16_t;
typedef __bf16 bf16x4 __attribute__((ext_vector_type(4)));
typedef __bf16 bf16x8 __attribute__((ext_vector_type(8)));
typedef float f32x4 __attribute__((ext_vector_type(4)));

#define DEVINL __device__ __forceinline__

// B=2, T=2048, D=1024, H=16, d=64, I=2816
#define TT 2048
#define DD 1024
#define HH 16
#define II 2816

DEVINL float waveSum(float v) {
#pragma unroll
  for (int m = 32; m >= 1; m >>= 1) v += __shfl_xor(v, m, 64);
  return v;
}

DEVINL float sigmoidf_(float z) { return 1.0f / (1.0f + __expf(-z)); }

DEVINL void gload_lds16(const bf16_t* g, bf16_t* l) {
  __builtin_amdgcn_global_load_lds((const __attribute__((address_space(1))) void*)g,
                                   (__attribute__((address_space(3))) void*)l, 16, 0, 0);
}

// ---------------- fused weight prep: cvt 5x DxD, pack GU interleaved, cvt down, zero stats ----
__global__ __launch_bounds__(256) void prep_kernel(const float* __restrict__ Wq,
                                                   const float* __restrict__ Wk,
                                                   const float* __restrict__ Wv,
                                                   const float* __restrict__ Wg,
                                                   const float* __restrict__ Wo,
                                                   const float* __restrict__ gate_w,
                                                   const float* __restrict__ up_w,
                                                   const float* __restrict__ down_w,
                                                   bf16_t* __restrict__ Wqkvg_bf,
                                                   bf16_t* __restrict__ Wo_bf,
                                                   bf16_t* __restrict__ GU_bf,
                                                   bf16_t* __restrict__ down_bf,
                                                   float* __restrict__ stats) {
  const int bid = blockIdx.x;
  const int tid = threadIdx.x;
  if (bid == 0 && tid < 64) stats[tid] = 0.f;
  if (bid < 5120) {
    const int which = bid >> 10;
    const float* src;
    bf16_t* dst;
    switch (which) {
      case 0: src = Wq; dst = Wqkvg_bf; break;
      case 1: src = Wk; dst = Wqkvg_bf + (size_t)DD * DD; break;
      case 2: src = Wv; dst = Wqkvg_bf + 2 * (size_t)DD * DD; break;
      case 3: src = Wg; dst = Wqkvg_bf + 3 * (size_t)DD * DD; break;
      default: src = Wo; dst = Wo_bf; break;
    }
    const int i = (bid & 1023) * 256 + tid;
    float4 v = reinterpret_cast<const float4*>(src)[i];
    bf16x4 o;
    o[0] = (bf16_t)v.x; o[1] = (bf16_t)v.y; o[2] = (bf16_t)v.z; o[3] = (bf16_t)v.w;
    reinterpret_cast<bf16x4*>(dst)[i] = o;
  } else if (bid < 10752) {
    // GU pack: dst row r: jb=r/32, s=r%32; s<16 -> gate row 16*jb+s ; else up
    const int r = bid - 5120;
    const int jb = r >> 5, s = r & 31;
    const float* src = (s < 16) ? (gate_w + (size_t)(jb * 16 + s) * DD)
                                : (up_w + (size_t)(jb * 16 + s - 16) * DD);
    float4 v = reinterpret_cast<const float4*>(src)[tid];
    bf16x4 o;
    o[0] = (bf16_t)v.x; o[1] = (bf16_t)v.y; o[2] = (bf16_t)v.z; o[3] = (bf16_t)v.w;
    reinterpret_cast<bf16x4*>(GU_bf + (size_t)r * DD)[tid] = o;
  } else {
    const int i = (bid - 10752) * 256 + tid;
    float4 v = reinterpret_cast<const float4*>(down_w)[i];
    bf16x4 o;
    o[0] = (bf16_t)v.x; o[1] = (bf16_t)v.y; o[2] = (bf16_t)v.z; o[3] = (bf16_t)v.w;
    reinterpret_cast<bf16x4*>(down_bf)[i] = o;
  }
}

// ---------------- RMSNorm (row of 1024) -> bf16 ----------------
__global__ __launch_bounds__(256) void rmsnorm_kernel(const float* __restrict__ x,
                                                      const float* __restrict__ w,
                                                      bf16_t* __restrict__ out) {
  const int row = blockIdx.x;
  const int tid = threadIdx.x;
  const float4 v = reinterpret_cast<const float4*>(x + (size_t)row * DD)[tid];
  float ss = v.x * v.x + v.y * v.y + v.z * v.z + v.w * v.w;
  ss = waveSum(ss);
  __shared__ float red[4];
  if ((tid & 63) == 0) red[tid >> 6] = ss;
  __syncthreads();
  const float total = red[0] + red[1] + red[2] + red[3];
  const float rstd = rsqrtf(total * (1.0f / (float)DD) + 1e-6f);
  const float4 wv = reinterpret_cast<const float4*>(w)[tid];
  bf16x4 o;
  o[0] = (bf16_t)(v.x * rstd * wv.x);
  o[1] = (bf16_t)(v.y * rstd * wv.y);
  o[2] = (bf16_t)(v.z * rstd * wv.z);
  o[3] = (bf16_t)(v.w * rstd * wv.w);
  reinterpret_cast<bf16x4*>(out + (size_t)row * DD)[tid] = o;
}

// ============ 128x256 8-wave BK=32 ring-3 GEMM (B^T input), 2 blocks/CU ============
// C[m,n] = sum_k A[m,k]*B[n,k].  M%128==0, N%256==0, K%32==0, K>=96.
// EPI: 2 = silu-fused bf16 (gate/up interleaved pairs, out stride II)
//      3 = qkv/g split bf16 (col<3072 -> O1 stride 3072; else sigmoid -> O2 stride DD)
template <int EPI>
__global__ __launch_bounds__(512, 4) void gemm128x256(const bf16_t* __restrict__ A,
                                                      const bf16_t* __restrict__ B,
                                                      bf16_t* __restrict__ O1,
                                                      bf16_t* __restrict__ O2,
                                                      int M, int N, int K) {
  extern __shared__ __align__(16) char lds[];
  const int tid = threadIdx.x;
  const int wid = tid >> 6;   // 0..7
  const int lane = tid & 63;
  const int wr = wid >> 2;    // 0..1  M-halves of 64
  const int wc = wid & 3;     // 0..3  N-quarters of 64

  // XCD-aware swizzle of flat block id (nwg % 8 == 0 for our grids: 512, 704)
  const int gx = gridDim.x;
  const int nwg = gx * gridDim.y;
  int flat = blockIdx.y * gx + blockIdx.x;
  flat = (flat & 7) * (nwg >> 3) + (flat >> 3);
  const int row0 = (flat / gx) * 128;
  const int col0 = (flat % gx) * 256;

  const int ls_row = lane >> 2;
  const int ls_col = ((lane & 3) ^ ((lane >> 3) & 3)) * 8;
  const bf16_t* gA = A + (size_t)(row0 + wid * 16 + ls_row) * K + ls_col;
  const bf16_t* gB = B + (size_t)(col0 + wid * 32 + ls_row) * K + ls_col;

  const int kq = lane >> 4;
  const int rl = lane & 15;
  const int xg = (rl >> 1) & 3;
  const int gsel = (kq ^ xg) << 4;  // byte offset of the lane's 16B granule

  f32x4 acc[4][4] = {};
  const int nt = K >> 5;  // >= 3

  auto stage = [&](int t) {
    char* slot = lds + (t % 3) * 24576;
    const int ko = t << 5;
    gload_lds16(gA + ko, (bf16_t*)(slot + wid * 1024));               // A: 128x32
#pragma unroll
    for (int j = 0; j < 2; ++j)                                       // B: 256x32
      gload_lds16(gB + (size_t)j * 16 * K + ko,
                  (bf16_t*)(slot + 8192 + wid * 2048 + j * 1024));
  };

  // prologue: stage tiles 0,1 ; wait tile 0 (3 = tile 1 remains in flight)
  stage(0); stage(1);
  asm volatile("s_waitcnt vmcnt(3)" ::: "memory");
  __builtin_amdgcn_s_barrier();
  __builtin_amdgcn_sched_barrier(0);

  for (int t = 0; t < nt; ++t) {
    if (t + 2 < nt) stage(t + 2);  // slot (t+2)%3 == (t-1)%3, read finished at t-1 barrier
    const char* ab = lds + (t % 3) * 24576;
    const char* bb = ab + 8192;
    bf16x8 aF[4], bF[4];
#pragma unroll
    for (int n = 0; n < 4; ++n)
      bF[n] = *reinterpret_cast<const bf16x8*>(bb + (wc * 64 + n * 16 + rl) * 64 + gsel);
#pragma unroll
    for (int m = 0; m < 4; ++m)
      aF[m] = *reinterpret_cast<const bf16x8*>(ab + (wr * 64 + m * 16 + rl) * 64 + gsel);
    __builtin_amdgcn_s_setprio(1);
#pragma unroll
    for (int m = 0; m < 4; ++m)
#pragma unroll
      for (int n = 0; n < 4; ++n)
        acc[m][n] = __builtin_amdgcn_mfma_f32_16x16x32_bf16(aF[m], bF[n], acc[m][n], 0, 0, 0);
    __builtin_amdgcn_s_setprio(0);
    if (t + 2 < nt) {
      asm volatile("s_waitcnt vmcnt(3)" ::: "memory");
    } else if (t + 2 == nt) {
      asm volatile("s_waitcnt vmcnt(0)" ::: "memory");
    }
    __builtin_amdgcn_s_barrier();
    __builtin_amdgcn_sched_barrier(0);
  }

  // ---- epilogue ----
  const int crow = row0 + wr * 64 + kq * 4;
  const int ccol = col0 + wc * 64 + rl;
  if (EPI == 2) {
    const int obase = (col0 + wc * 64) / 2 + rl;
#pragma unroll
    for (int m = 0; m < 4; ++m)
#pragma unroll
      for (int p = 0; p < 2; ++p)
#pragma unroll
        for (int r = 0; r < 4; ++r) {
          const float g = acc[m][2 * p][r];
          const float u = acc[m][2 * p + 1][r];
          O1[(size_t)(crow + m * 16 + r) * II + (obase + p * 16)] =
              (bf16_t)(g * sigmoidf_(g) * u);
        }
  } else {  // EPI == 3
    if (col0 < 3072) {
#pragma unroll
      for (int m = 0; m < 4; ++m)
#pragma unroll
        for (int n = 0; n < 4; ++n)
#pragma unroll
          for (int r = 0; r < 4; ++r)
            O1[(size_t)(crow + m * 16 + r) * 3072 + (ccol + n * 16)] = (bf16_t)acc[m][n][r];
    } else {
#pragma unroll
      for (int m = 0; m < 4; ++m)
#pragma unroll
        for (int n = 0; n < 4; ++n)
#pragma unroll
          for (int r = 0; r < 4; ++r)
            O2[(size_t)(crow + m * 16 + r) * DD + (ccol + n * 16 - 3072)] =
                (bf16_t)sigmoidf_(acc[m][n][r]);
    }
  }
}

// -------- 64x128 4-wave BK=32 GEMM (N=1024: Wo, down), C = acc + addsrc --------
// Grid (N/128) x (M/64) = 8 x 64 = 512 blocks -> 2 blocks/CU (m114 overlap regime).
// 12KB LDS, same granule swizzle. Wave w owns all 64 rows x cols [w*32, w*32+32).
__global__ __launch_bounds__(256) void gemm64x128(const bf16_t* __restrict__ A,
                                                  const bf16_t* __restrict__ B,
                                                  float* __restrict__ C,
                                                  const float* __restrict__ addsrc,
                                                  int M, int N, int K) {
  __shared__ __align__(16) bf16_t smA[64 * 32];    // 4 KB
  __shared__ __align__(16) bf16_t smB[128 * 32];   // 8 KB
  const int tid = threadIdx.x;
  const int wid = tid >> 6;  // 0..3
  const int lane = tid & 63;
  const int row0 = blockIdx.y * 64;
  const int col0 = blockIdx.x * 128;

  f32x4 acc[4][2] = {};

  const int ls_row = lane >> 2;
  const int ls_col = ((lane & 3) ^ ((lane >> 3) & 3)) * 8;  // inverse-swizzled source
  const bf16_t* gA = A + (size_t)(row0 + wid * 16 + ls_row) * K + ls_col;
  const bf16_t* gB = B + (size_t)(col0 + wid * 32 + ls_row) * K + ls_col;

  const int rl = lane & 15;
  const int kq = lane >> 4;
  const int xg = (rl >> 1) & 3;
  const int ge = (kq ^ xg) * 8;  // element offset of the lane's granule

  for (int k0 = 0; k0 < K; k0 += 32) {
    gload_lds16(gA + k0, smA + wid * 512);                 // A: 64x32 (1 issue/wave)
#pragma unroll
    for (int j = 0; j < 2; ++j)                            // B: 128x32 (2 issues/wave)
      gload_lds16(gB + (size_t)j * 16 * K + k0, smB + wid * 1024 + j * 512);
    __syncthreads();
    bf16x8 aF[4], bF[2];
#pragma unroll
    for (int m = 0; m < 4; ++m)
      aF[m] = *reinterpret_cast<const bf16x8*>(smA + (m * 16 + rl) * 32 + ge);
#pragma unroll
    for (int n = 0; n < 2; ++n)
      bF[n] = *reinterpret_cast<const bf16x8*>(smB + (wid * 32 + n * 16 + rl) * 32 + ge);
#pragma unroll
    for (int m = 0; m < 4; ++m)
#pragma unroll
      for (int n = 0; n < 2; ++n)
        acc[m][n] = __builtin_amdgcn_mfma_f32_16x16x32_bf16(aF[m], bF[n], acc[m][n], 0, 0, 0);
    __syncthreads();
  }

  const int ccol = col0 + wid * 32 + rl;
#pragma unroll
  for (int m = 0; m < 4; ++m)
#pragma unroll
    for (int n = 0; n < 2; ++n)
#pragma unroll
      for (int r = 0; r < 4; ++r) {
        const size_t idx = (size_t)(row0 + m * 16 + kq * 4 + r) * N + (ccol + n * 16);
        C[idx] = acc[m][n][r] + addsrc[idx];
      }
}

// ---------------- RetNet windowed decay scan on MFMA + fused GN partial stats ----------------
__global__ __launch_bounds__(256) void retscan_mfma(const bf16_t* __restrict__ qkv,
                                                    const float* __restrict__ gamma,
                                                    float* __restrict__ y,
                                                    float* __restrict__ stats) {
  const int c = blockIdx.x;
  const int bh = blockIdx.y;
  const int b = bh >> 4;
  const int h = bh & 15;
  const int tid = threadIdx.x;
  const int w = tid >> 6;
  const int lane = tid & 63;
  const int kq = lane >> 4;
  const int rl = lane & 15;

  __shared__ __align__(16) bf16_t K_lds[128 * 64];    // [sw][j]   swizzled
  __shared__ __align__(16) bf16_t VT_lds[64 * 128];   // [e][sw]   swizzled
  __shared__ __align__(16) bf16_t P_lds[64 * 128];    // [i][sw]   swizzled
  __shared__ float rs[4][2];

  const size_t rstr = 3 * DD;
  const bf16_t* base = qkv + (size_t)(b * TT) * rstr + h * 64;  // Q
  const bf16_t* kgl = base + DD;
  const bf16_t* vgl = base + 2 * DD;

  // ---- stage K (swizzled) and V^T (transposed, swizzled) ----
  for (int g = tid; g < 1024; g += 256) {
    const int sw = g >> 3, gr = g & 7;
    const int t = c * 64 - 64 + sw;
    bf16x8 kv = {};
    bf16x8 vv = {};
    if (t >= 0) {
      kv = *reinterpret_cast<const bf16x8*>(kgl + (size_t)t * rstr + gr * 8);
      vv = *reinterpret_cast<const bf16x8*>(vgl + (size_t)t * rstr + gr * 8);
    }
    *reinterpret_cast<bf16x8*>(K_lds + sw * 64 + ((gr ^ (sw & 7)) << 3)) = kv;
#pragma unroll
    for (int j = 0; j < 8; ++j) {
      const int e = gr * 8 + j;
      const int gs = (sw >> 3) ^ (e & 7);
      VT_lds[e * 128 + (gs << 3) + (sw & 7)] = vv[j];
    }
  }

  // ---- Q fragments (direct from global; rows i0..i0+15 of this wave) ----
  const int i0 = w * 16;
  const bf16_t* qrow = base + (size_t)(c * 64 + i0 + rl) * rstr;
  bf16x8 qF0 = *reinterpret_cast<const bf16x8*>(qrow + kq * 8);
  bf16x8 qF1 = *reinterpret_cast<const bf16x8*>(qrow + 32 + kq * 8);
  const float gam = sigmoidf_(gamma[h]);
  const float l2g = __log2f(gam);
  const float gi16 = exp2f(-16.f * l2g);  // gam^-16: lag decreases by 16 per sw-tile

  __syncthreads();

  // ---- QK^T: S[i=i0+kq*4+r][sw=st*16+rl] ----
  f32x4 S[8];
#pragma unroll
  for (int st = 0; st < 8; ++st) {
    const int sw = st * 16 + rl;
    const bf16_t* krow = K_lds + sw * 64;
    bf16x8 kF0 = *reinterpret_cast<const bf16x8*>(krow + ((kq ^ (sw & 7)) << 3));
    bf16x8 kF1 = *reinterpret_cast<const bf16x8*>(krow + (((4 + kq) ^ (sw & 7)) << 3));
    f32x4 s = {};
    s = __builtin_amdgcn_mfma_f32_16x16x32_bf16(qF0, kF0, s, 0, 0, 0);
    s = __builtin_amdgcn_mfma_f32_16x16x32_bf16(qF1, kF1, s, 0, 0, 0);
    S[st] = s;
  }

  // ---- decay * mask -> bf16 P (own rows only) ----
  float wgt[4];
  int lag[4];
#pragma unroll
  for (int r = 0; r < 4; ++r) {
    lag[r] = 64 + i0 + kq * 4 + r - rl;  // at st=0; always >=0 here
    wgt[r] = exp2f((float)lag[r] * l2g);
  }
#pragma unroll
  for (int st = 0; st < 8; ++st) {
    const int sw = st * 16 + rl;
#pragma unroll
    for (int r = 0; r < 4; ++r) {
      const float p = (lag[r] >= 0) ? S[st][r] * wgt[r] : 0.f;
      const int i = i0 + kq * 4 + r;
      const int gs = (sw >> 3) ^ (i & 7);
      P_lds[i * 128 + (gs << 3) + (sw & 7)] = (bf16_t)p;
      lag[r] -= 16;
      wgt[r] *= gi16;
    }
  }
  asm volatile("s_waitcnt lgkmcnt(0)" ::: "memory");
  __builtin_amdgcn_sched_barrier(0);

  // ---- PV: Y[i][e] = sum_sw P[i][sw] * V[sw][e] ----
  f32x4 Y[4] = {};
#pragma unroll
  for (int ks = 0; ks < 4; ++ks) {
    const int ia = i0 + rl;
    const int ga = (ks * 4 + kq) ^ (ia & 7);
    bf16x8 aF = *reinterpret_cast<const bf16x8*>(P_lds + ia * 128 + (ga << 3));
#pragma unroll
    for (int et = 0; et < 4; ++et) {
      const int e = et * 16 + rl;
      const int gb = (ks * 4 + kq) ^ (e & 7);
      bf16x8 bF = *reinterpret_cast<const bf16x8*>(VT_lds + e * 128 + (gb << 3));
      Y[et] = __builtin_amdgcn_mfma_f32_16x16x32_bf16(aF, bF, Y[et], 0, 0, 0);
    }
  }

  // ---- store y (f32) + fused GN partial stats ----
  float s = 0.f, ss = 0.f;
  const size_t ybase = (size_t)(b * TT + c * 64 + i0 + kq * 4) * DD + h * 64 + rl;
#pragma unroll
  for (int et = 0; et < 4; ++et)
#pragma unroll
    for (int r = 0; r < 4; ++r) {
      const float v = Y[et][r];
      s += v;
      ss += v * v;
      y[ybase + (size_t)r * DD + et * 16] = v;
    }
  s = waveSum(s);
  ss = waveSum(ss);
  if (lane == 0) { rs[w][0] = s; rs[w][1] = ss; }
  __syncthreads();
  if (tid == 0) {
    atomicAdd(&stats[bh * 2], rs[0][0] + rs[1][0] + rs[2][0] + rs[3][0]);
    atomicAdd(&stats[bh * 2 + 1], rs[0][1] + rs[1][1] + rs[2][1] + rs[3][1]);
  }
}

// ---------------- GroupNorm apply (finalize stats) * pre-sigmoided gate -> bf16 ----------------
__global__ __launch_bounds__(256) void gn_apply_kernel(const float* __restrict__ y,
                                                       const float* __restrict__ stats,
                                                       const bf16_t* __restrict__ gsig,
                                                       const float* __restrict__ gn_w,
                                                       const float* __restrict__ gn_b,
                                                       bf16_t* __restrict__ out) {
  const int row = blockIdx.x;
  const int tid = threadIdx.x;
  const int col = tid * 4;
  const int b = row >> 11;
  const int h = col >> 6;
  const float S = stats[(b * HH + h) * 2];
  const float SS = stats[(b * HH + h) * 2 + 1];
  const float inv = 1.0f / ((float)TT * 64.0f);
  const float mean = S * inv;
  const float var = SS * inv - mean * mean;
  const float rstd = rsqrtf(var + 1e-5f);
  float4 v = reinterpret_cast<const float4*>(y + (size_t)row * DD)[tid];
  float4 wv = reinterpret_cast<const float4*>(gn_w)[tid];
  float4 bv = reinterpret_cast<const float4*>(gn_b)[tid];
  bf16x4 gv = reinterpret_cast<const bf16x4*>(gsig + (size_t)row * DD)[tid];
  bf16x4 o;
  o[0] = (bf16_t)((((v.x - mean) * rstd) * wv.x + bv.x) * (float)gv[0]);
  o[1] = (bf16_t)((((v.y - mean) * rstd) * wv.y + bv.y) * (float)gv[1]);
  o[2] = (bf16_t)((((v.z - mean) * rstd) * wv.z + bv.z) * (float)gv[2]);
  o[3] = (bf16_t)((((v.w - mean) * rstd) * wv.w + bv.w) * (float)gv[3]);
  reinterpret_cast<bf16x4*>(out + (size_t)row * DD)[tid] = o;
}

extern "C" void kernel_launch(void* const* d_in, const int* in_sizes, int n_in,
                              void* d_out, int out_size, void* d_ws, size_t ws_size,
                              hipStream_t stream) {
  const float* x = (const float*)d_in[0];
  const float* ln1_w = (const float*)d_in[1];
  const float* ln2_w = (const float*)d_in[2];
  const float* Wq = (const float*)d_in[3];
  const float* Wk = (const float*)d_in[4];
  const float* Wv = (const float*)d_in[5];
  const float* Wg = (const float*)d_in[6];
  const float* Wo = (const float*)d_in[7];
  const float* gamma = (const float*)d_in[8];
  const float* gn_w = (const float*)d_in[9];
  const float* gn_b = (const float*)d_in[10];
  const float* gate_w = (const float*)d_in[11];
  const float* up_w = (const float*)d_in[12];
  const float* down_w = (const float*)d_in[13];
  float* out = (float*)d_out;

  const int M = 2 * TT;  // 4096

  char* ws = (char*)d_ws;
  size_t off = 0;
  auto alloc = [&](size_t bytes) -> void* {
    void* p = ws + off;
    off += (bytes + 255) & ~(size_t)255;
    return p;
  };
  bf16_t* h_bf = (bf16_t*)alloc((size_t)M * DD * 2);
  bf16_t* Wqkvg_bf = (bf16_t*)alloc((size_t)4 * DD * DD * 2);
  bf16_t* Wo_bf = (bf16_t*)alloc((size_t)DD * DD * 2);
  bf16_t* GU_bf = (bf16_t*)alloc((size_t)2 * II * DD * 2);
  bf16_t* down_bf = (bf16_t*)alloc((size_t)DD * II * 2);
  bf16_t* qkv_bf = (bf16_t*)alloc((size_t)M * 3 * DD * 2);
  bf16_t* gsig = (bf16_t*)alloc((size_t)M * DD * 2);
  float* yBuf = (float*)alloc((size_t)M * DD * 4);
  bf16_t* ygated = (bf16_t*)alloc((size_t)M * DD * 2);
  bf16_t* act = (bf16_t*)alloc((size_t)M * II * 2);
  float* stats = (float*)alloc(64 * 4);
  (void)ws_size; (void)in_sizes; (void)n_in; (void)out_size;

  float* x2 = yBuf;

  // fused weight prep (+ stats zeroing)
  prep_kernel<<<13568, 256, 0, stream>>>(Wq, Wk, Wv, Wg, Wo, gate_w, up_w, down_w,
                                         Wqkvg_bf, Wo_bf, GU_bf, down_bf, stats);

  // h = rmsnorm(x) -> bf16
  rmsnorm_kernel<<<M, 256, 0, stream>>>(x, ln1_w, h_bf);

  // qkv (bf16) + sigmoid(g) (bf16) = h @ [Wq;Wk;Wv;Wg]^T
  {
    dim3 g(4 * DD / 256, M / 128);  // 16 x 32 = 512 blocks = 2/CU
    gemm128x256<3><<<g, 512, 73728, stream>>>(h_bf, Wqkvg_bf, qkv_bf, gsig, M, 4 * DD, DD);
  }

  // windowed decay scan (MFMA) -> y (f32) + partial GN stats
  {
    dim3 g(TT / 64, 2 * HH);
    retscan_mfma<<<g, 256, 0, stream>>>(qkv_bf, gamma, yBuf, stats);
  }

  // GN apply * sigmoid(g)
  gn_apply_kernel<<<M, 256, 0, stream>>>(yBuf, stats, gsig, gn_w, gn_b, ygated);

  // x2 = x + ygated @ Wo^T   (overwrites yBuf; gn_apply already consumed it)
  {
    dim3 g(DD / 128, M / 64);  // 8 x 64 = 512 blocks = 2/CU
    gemm64x128<<<g, 256, 0, stream>>>(ygated, Wo_bf, x2, x, M, DD, DD);
  }

  // h2 = rmsnorm(x2) -> bf16
  rmsnorm_kernel<<<M, 256, 0, stream>>>(x2, ln2_w, h_bf);

  // act = silu(h2 @ gate^T) * (h2 @ up^T) -> bf16, fused epilogue
  {
    dim3 g(2 * II / 256, M / 128);  // 22 x 32 = 704 blocks
    gemm128x256<2><<<g, 512, 73728, stream>>>(h_bf, GU_bf, act, nullptr, M, 2 * II, DD);
  }

  // out = x2 + act @ down^T
  {
    dim3 g(DD / 128, M / 64);  // 512 blocks
    gemm64x128<<<g, 256, 0, stream>>>(act, down_bf, out, x2, M, DD, II);
  }
}

// Round 14
// 222.811 us; speedup vs baseline: 1.4046x; 1.1083x over previous
//
#include <hip/hip_runtime.h>
#include <hip/hip_bf16.h>
#include <cstdint>
#include <cstddef>

typedef __bf16 bf16_t;
typedef __bf16 bf16x4 __attribute__((ext_vector_type(4)));
typedef __bf16 bf16x8 __attribute__((ext_vector_type(8)));
typedef float f32x4 __attribute__((ext_vector_type(4)));

#define DEVINL __device__ __forceinline__

// B=2, T=2048, D=1024, H=16, d=64, I=2816
#define TT 2048
#define DD 1024
#define HH 16
#define II 2816

DEVINL float waveSum(float v) {
#pragma unroll
  for (int m = 32; m >= 1; m >>= 1) v += __shfl_xor(v, m, 64);
  return v;
}

DEVINL float sigmoidf_(float z) { return 1.0f / (1.0f + __expf(-z)); }

DEVINL void gload_lds16(const bf16_t* g, bf16_t* l) {
  __builtin_amdgcn_global_load_lds((const __attribute__((address_space(1))) void*)g,
                                   (__attribute__((address_space(3))) void*)l, 16, 0, 0);
}

// ---------------- fused weight prep: cvt 5x DxD, pack GU interleaved, cvt down, zero stats ----
__global__ __launch_bounds__(256) void prep_kernel(const float* __restrict__ Wq,
                                                   const float* __restrict__ Wk,
                                                   const float* __restrict__ Wv,
                                                   const float* __restrict__ Wg,
                                                   const float* __restrict__ Wo,
                                                   const float* __restrict__ gate_w,
                                                   const float* __restrict__ up_w,
                                                   const float* __restrict__ down_w,
                                                   bf16_t* __restrict__ Wqkvg_bf,
                                                   bf16_t* __restrict__ Wo_bf,
                                                   bf16_t* __restrict__ GU_bf,
                                                   bf16_t* __restrict__ down_bf,
                                                   float* __restrict__ stats) {
  const int bid = blockIdx.x;
  const int tid = threadIdx.x;
  if (bid == 0 && tid < 64) stats[tid] = 0.f;
  if (bid < 5120) {
    const int which = bid >> 10;
    const float* src;
    bf16_t* dst;
    switch (which) {
      case 0: src = Wq; dst = Wqkvg_bf; break;
      case 1: src = Wk; dst = Wqkvg_bf + (size_t)DD * DD; break;
      case 2: src = Wv; dst = Wqkvg_bf + 2 * (size_t)DD * DD; break;
      case 3: src = Wg; dst = Wqkvg_bf + 3 * (size_t)DD * DD; break;
      default: src = Wo; dst = Wo_bf; break;
    }
    const int i = (bid & 1023) * 256 + tid;
    float4 v = reinterpret_cast<const float4*>(src)[i];
    bf16x4 o;
    o[0] = (bf16_t)v.x; o[1] = (bf16_t)v.y; o[2] = (bf16_t)v.z; o[3] = (bf16_t)v.w;
    reinterpret_cast<bf16x4*>(dst)[i] = o;
  } else if (bid < 10752) {
    // GU pack: dst row r: jb=r/32, s=r%32; s<16 -> gate row 16*jb+s ; else up
    const int r = bid - 5120;
    const int jb = r >> 5, s = r & 31;
    const float* src = (s < 16) ? (gate_w + (size_t)(jb * 16 + s) * DD)
                                : (up_w + (size_t)(jb * 16 + s - 16) * DD);
    float4 v = reinterpret_cast<const float4*>(src)[tid];
    bf16x4 o;
    o[0] = (bf16_t)v.x; o[1] = (bf16_t)v.y; o[2] = (bf16_t)v.z; o[3] = (bf16_t)v.w;
    reinterpret_cast<bf16x4*>(GU_bf + (size_t)r * DD)[tid] = o;
  } else {
    const int i = (bid - 10752) * 256 + tid;
    float4 v = reinterpret_cast<const float4*>(down_w)[i];
    bf16x4 o;
    o[0] = (bf16_t)v.x; o[1] = (bf16_t)v.y; o[2] = (bf16_t)v.z; o[3] = (bf16_t)v.w;
    reinterpret_cast<bf16x4*>(down_bf)[i] = o;
  }
}

// ---------------- RMSNorm (row of 1024) -> bf16 ----------------
__global__ __launch_bounds__(256) void rmsnorm_kernel(const float* __restrict__ x,
                                                      const float* __restrict__ w,
                                                      bf16_t* __restrict__ out) {
  const int row = blockIdx.x;
  const int tid = threadIdx.x;
  const float4 v = reinterpret_cast<const float4*>(x + (size_t)row * DD)[tid];
  float ss = v.x * v.x + v.y * v.y + v.z * v.z + v.w * v.w;
  ss = waveSum(ss);
  __shared__ float red[4];
  if ((tid & 63) == 0) red[tid >> 6] = ss;
  __syncthreads();
  const float total = red[0] + red[1] + red[2] + red[3];
  const float rstd = rsqrtf(total * (1.0f / (float)DD) + 1e-6f);
  const float4 wv = reinterpret_cast<const float4*>(w)[tid];
  bf16x4 o;
  o[0] = (bf16_t)(v.x * rstd * wv.x);
  o[1] = (bf16_t)(v.y * rstd * wv.y);
  o[2] = (bf16_t)(v.z * rstd * wv.z);
  o[3] = (bf16_t)(v.w * rstd * wv.w);
  reinterpret_cast<bf16x4*>(out + (size_t)row * DD)[tid] = o;
}

// ============ 128x256 8-wave BK=32 ring-3 GEMM (B^T input), 2 blocks/CU ============
// C[m,n] = sum_k A[m,k]*B[n,k].  M%128==0, N%256==0, K%32==0, K>=96.
// EPI: 2 = silu-fused bf16 (gate/up interleaved pairs, out stride II)
//      3 = qkv/g split bf16 (col<3072 -> O1 stride 3072; else sigmoid -> O2 stride DD)
template <int EPI>
__global__ __launch_bounds__(512, 4) void gemm128x256(const bf16_t* __restrict__ A,
                                                      const bf16_t* __restrict__ B,
                                                      bf16_t* __restrict__ O1,
                                                      bf16_t* __restrict__ O2,
                                                      int M, int N, int K) {
  extern __shared__ __align__(16) char lds[];
  const int tid = threadIdx.x;
  const int wid = tid >> 6;   // 0..7
  const int lane = tid & 63;
  const int wr = wid >> 2;    // 0..1  M-halves of 64
  const int wc = wid & 3;     // 0..3  N-quarters of 64

  // XCD-aware swizzle of flat block id (nwg % 8 == 0 for our grids: 512, 704)
  const int gx = gridDim.x;
  const int nwg = gx * gridDim.y;
  int flat = blockIdx.y * gx + blockIdx.x;
  flat = (flat & 7) * (nwg >> 3) + (flat >> 3);
  const int row0 = (flat / gx) * 128;
  const int col0 = (flat % gx) * 256;

  const int ls_row = lane >> 2;
  const int ls_col = ((lane & 3) ^ ((lane >> 3) & 3)) * 8;
  const bf16_t* gA = A + (size_t)(row0 + wid * 16 + ls_row) * K + ls_col;
  const bf16_t* gB = B + (size_t)(col0 + wid * 32 + ls_row) * K + ls_col;

  const int kq = lane >> 4;
  const int rl = lane & 15;
  const int xg = (rl >> 1) & 3;
  const int gsel = (kq ^ xg) << 4;  // byte offset of the lane's 16B granule

  f32x4 acc[4][4] = {};
  const int nt = K >> 5;  // >= 3

  auto stage = [&](int t) {
    char* slot = lds + (t % 3) * 24576;
    const int ko = t << 5;
    gload_lds16(gA + ko, (bf16_t*)(slot + wid * 1024));               // A: 128x32
#pragma unroll
    for (int j = 0; j < 2; ++j)                                       // B: 256x32
      gload_lds16(gB + (size_t)j * 16 * K + ko,
                  (bf16_t*)(slot + 8192 + wid * 2048 + j * 1024));
  };

  // prologue: stage tiles 0,1 ; wait tile 0 (3 = tile 1 remains in flight)
  stage(0); stage(1);
  asm volatile("s_waitcnt vmcnt(3)" ::: "memory");
  __builtin_amdgcn_s_barrier();
  __builtin_amdgcn_sched_barrier(0);

  for (int t = 0; t < nt; ++t) {
    if (t + 2 < nt) stage(t + 2);  // slot (t+2)%3 == (t-1)%3, read finished at t-1 barrier
    const char* ab = lds + (t % 3) * 24576;
    const char* bb = ab + 8192;
    bf16x8 aF[4], bF[4];
#pragma unroll
    for (int n = 0; n < 4; ++n)
      bF[n] = *reinterpret_cast<const bf16x8*>(bb + (wc * 64 + n * 16 + rl) * 64 + gsel);
#pragma unroll
    for (int m = 0; m < 4; ++m)
      aF[m] = *reinterpret_cast<const bf16x8*>(ab + (wr * 64 + m * 16 + rl) * 64 + gsel);
    __builtin_amdgcn_s_setprio(1);
#pragma unroll
    for (int m = 0; m < 4; ++m)
#pragma unroll
      for (int n = 0; n < 4; ++n)
        acc[m][n] = __builtin_amdgcn_mfma_f32_16x16x32_bf16(aF[m], bF[n], acc[m][n], 0, 0, 0);
    __builtin_amdgcn_s_setprio(0);
    if (t + 2 < nt) {
      asm volatile("s_waitcnt vmcnt(3)" ::: "memory");
    } else if (t + 2 == nt) {
      asm volatile("s_waitcnt vmcnt(0)" ::: "memory");
    }
    __builtin_amdgcn_s_barrier();
    __builtin_amdgcn_sched_barrier(0);
  }

  // ---- epilogue ----
  const int crow = row0 + wr * 64 + kq * 4;
  const int ccol = col0 + wc * 64 + rl;
  if (EPI == 2) {
    const int obase = (col0 + wc * 64) / 2 + rl;
#pragma unroll
    for (int m = 0; m < 4; ++m)
#pragma unroll
      for (int p = 0; p < 2; ++p)
#pragma unroll
        for (int r = 0; r < 4; ++r) {
          const float g = acc[m][2 * p][r];
          const float u = acc[m][2 * p + 1][r];
          O1[(size_t)(crow + m * 16 + r) * II + (obase + p * 16)] =
              (bf16_t)(g * sigmoidf_(g) * u);
        }
  } else {  // EPI == 3
    if (col0 < 3072) {
#pragma unroll
      for (int m = 0; m < 4; ++m)
#pragma unroll
        for (int n = 0; n < 4; ++n)
#pragma unroll
          for (int r = 0; r < 4; ++r)
            O1[(size_t)(crow + m * 16 + r) * 3072 + (ccol + n * 16)] = (bf16_t)acc[m][n][r];
    } else {
#pragma unroll
      for (int m = 0; m < 4; ++m)
#pragma unroll
        for (int n = 0; n < 4; ++n)
#pragma unroll
          for (int r = 0; r < 4; ++r)
            O2[(size_t)(crow + m * 16 + r) * DD + (ccol + n * 16 - 3072)] =
                (bf16_t)sigmoidf_(acc[m][n][r]);
    }
  }
}

// -------- 64x128 4-wave BK=32 ring-5 GEMM (N=1024: Wo, down), C = acc + addsrc --------
// Grid MUST be (8, 64). Block remap: d=by*8+bx -> col=d>>6, row=d&63 pins A-band r to
// XCD r%8 (per-XCD A working set 2.9MB fits L2; A fetched ~once chip-wide).
// Ring-5 LDS (30KB, 4 blocks/CU), depth-4 prefetch, counted vmcnt(9/6/3/0).
__global__ __launch_bounds__(256) void gemm64x128(const bf16_t* __restrict__ A,
                                                  const bf16_t* __restrict__ B,
                                                  float* __restrict__ C,
                                                  const float* __restrict__ addsrc,
                                                  int M, int N, int K) {
  __shared__ __align__(16) bf16_t sm[5 * 6144];  // slot = A 64x32 (2048) + B 128x32 (4096)
  const int tid = threadIdx.x;
  const int wid = tid >> 6;  // 0..3
  const int lane = tid & 63;
  const int d = blockIdx.y * 8 + blockIdx.x;
  const int row0 = (d & 63) * 64;
  const int col0 = (d >> 6) * 128;

  f32x4 acc[4][2] = {};

  const int ls_row = lane >> 2;
  const int ls_col = ((lane & 3) ^ ((lane >> 3) & 3)) * 8;  // inverse-swizzled source
  const bf16_t* gA = A + (size_t)(row0 + wid * 16 + ls_row) * K + ls_col;
  const bf16_t* gB = B + (size_t)(col0 + wid * 32 + ls_row) * K + ls_col;

  const int rl = lane & 15;
  const int kq = lane >> 4;
  const int xg = (rl >> 1) & 3;
  const int ge = (kq ^ xg) * 8;  // element offset of the lane's granule

  const int nt = K >> 5;  // 32 (Wo) or 88 (down); >= 5
  auto stage = [&](int t) {
    bf16_t* slot = sm + (t % 5) * 6144;
    const int ko = t << 5;
    gload_lds16(gA + ko, slot + wid * 512);                     // A: 1 issue/wave
#pragma unroll
    for (int j = 0; j < 2; ++j)                                 // B: 2 issues/wave
      gload_lds16(gB + (size_t)j * 16 * K + ko, slot + 2048 + wid * 1024 + j * 512);
  };

  // prologue: stage tiles 0..3 (12 loads); vmcnt(9) -> tile 0 landed, 3 tiles in flight
  stage(0); stage(1); stage(2); stage(3);
  asm volatile("s_waitcnt vmcnt(9)" ::: "memory");
  __builtin_amdgcn_s_barrier();
  __builtin_amdgcn_sched_barrier(0);

  for (int t = 0; t < nt; ++t) {
    if (t + 5 <= nt) stage(t + 4);  // slot (t+4)%5 == (t-1)%5: reads retired at t-1 barrier
    const bf16_t* slot = sm + (t % 5) * 6144;
    bf16x8 aF[4], bF[2];
#pragma unroll
    for (int m = 0; m < 4; ++m)
      aF[m] = *reinterpret_cast<const bf16x8*>(slot + (m * 16 + rl) * 32 + ge);
#pragma unroll
    for (int n = 0; n < 2; ++n)
      bF[n] = *reinterpret_cast<const bf16x8*>(slot + 2048 + (wid * 32 + n * 16 + rl) * 32 + ge);
    __builtin_amdgcn_s_setprio(1);
#pragma unroll
    for (int m = 0; m < 4; ++m)
#pragma unroll
      for (int n = 0; n < 2; ++n)
        acc[m][n] = __builtin_amdgcn_mfma_f32_16x16x32_bf16(aF[m], bF[n], acc[m][n], 0, 0, 0);
    __builtin_amdgcn_s_setprio(0);
    // counted drain: ensure tile t+1 landed; keep later tiles in flight
    if (t + 5 <= nt) {
      asm volatile("s_waitcnt vmcnt(9)" ::: "memory");
    } else if (t + 4 == nt) {
      asm volatile("s_waitcnt vmcnt(6)" ::: "memory");
    } else if (t + 3 == nt) {
      asm volatile("s_waitcnt vmcnt(3)" ::: "memory");
    } else if (t + 2 == nt) {
      asm volatile("s_waitcnt vmcnt(0)" ::: "memory");
    }
    __builtin_amdgcn_s_barrier();
    __builtin_amdgcn_sched_barrier(0);
  }

  const int ccol = col0 + wid * 32 + rl;
#pragma unroll
  for (int m = 0; m < 4; ++m)
#pragma unroll
    for (int n = 0; n < 2; ++n)
#pragma unroll
      for (int r = 0; r < 4; ++r) {
        const size_t idx = (size_t)(row0 + m * 16 + kq * 4 + r) * N + (ccol + n * 16);
        C[idx] = acc[m][n][r] + addsrc[idx];
      }
}

// ---------------- RetNet windowed decay scan on MFMA + fused GN partial stats ----------------
__global__ __launch_bounds__(256) void retscan_mfma(const bf16_t* __restrict__ qkv,
                                                    const float* __restrict__ gamma,
                                                    float* __restrict__ y,
                                                    float* __restrict__ stats) {
  const int c = blockIdx.x;
  const int bh = blockIdx.y;
  const int b = bh >> 4;
  const int h = bh & 15;
  const int tid = threadIdx.x;
  const int w = tid >> 6;
  const int lane = tid & 63;
  const int kq = lane >> 4;
  const int rl = lane & 15;

  __shared__ __align__(16) bf16_t K_lds[128 * 64];    // [sw][j]   swizzled
  __shared__ __align__(16) bf16_t VT_lds[64 * 128];   // [e][sw]   swizzled
  __shared__ __align__(16) bf16_t P_lds[64 * 128];    // [i][sw]   swizzled
  __shared__ float rs[4][2];

  const size_t rstr = 3 * DD;
  const bf16_t* base = qkv + (size_t)(b * TT) * rstr + h * 64;  // Q
  const bf16_t* kgl = base + DD;
  const bf16_t* vgl = base + 2 * DD;

  // ---- stage K (swizzled) and V^T (transposed, swizzled) ----
  for (int g = tid; g < 1024; g += 256) {
    const int sw = g >> 3, gr = g & 7;
    const int t = c * 64 - 64 + sw;
    bf16x8 kv = {};
    bf16x8 vv = {};
    if (t >= 0) {
      kv = *reinterpret_cast<const bf16x8*>(kgl + (size_t)t * rstr + gr * 8);
      vv = *reinterpret_cast<const bf16x8*>(vgl + (size_t)t * rstr + gr * 8);
    }
    *reinterpret_cast<bf16x8*>(K_lds + sw * 64 + ((gr ^ (sw & 7)) << 3)) = kv;
#pragma unroll
    for (int j = 0; j < 8; ++j) {
      const int e = gr * 8 + j;
      const int gs = (sw >> 3) ^ (e & 7);
      VT_lds[e * 128 + (gs << 3) + (sw & 7)] = vv[j];
    }
  }

  // ---- Q fragments (direct from global; rows i0..i0+15 of this wave) ----
  const int i0 = w * 16;
  const bf16_t* qrow = base + (size_t)(c * 64 + i0 + rl) * rstr;
  bf16x8 qF0 = *reinterpret_cast<const bf16x8*>(qrow + kq * 8);
  bf16x8 qF1 = *reinterpret_cast<const bf16x8*>(qrow + 32 + kq * 8);
  const float gam = sigmoidf_(gamma[h]);
  const float l2g = __log2f(gam);
  const float gi16 = exp2f(-16.f * l2g);  // gam^-16: lag decreases by 16 per sw-tile

  __syncthreads();

  // ---- QK^T: S[i=i0+kq*4+r][sw=st*16+rl] ----
  f32x4 S[8];
#pragma unroll
  for (int st = 0; st < 8; ++st) {
    const int sw = st * 16 + rl;
    const bf16_t* krow = K_lds + sw * 64;
    bf16x8 kF0 = *reinterpret_cast<const bf16x8*>(krow + ((kq ^ (sw & 7)) << 3));
    bf16x8 kF1 = *reinterpret_cast<const bf16x8*>(krow + (((4 + kq) ^ (sw & 7)) << 3));
    f32x4 s = {};
    s = __builtin_amdgcn_mfma_f32_16x16x32_bf16(qF0, kF0, s, 0, 0, 0);
    s = __builtin_amdgcn_mfma_f32_16x16x32_bf16(qF1, kF1, s, 0, 0, 0);
    S[st] = s;
  }

  // ---- decay * mask -> bf16 P (own rows only) ----
  float wgt[4];
  int lag[4];
#pragma unroll
  for (int r = 0; r < 4; ++r) {
    lag[r] = 64 + i0 + kq * 4 + r - rl;  // at st=0; always >=0 here
    wgt[r] = exp2f((float)lag[r] * l2g);
  }
#pragma unroll
  for (int st = 0; st < 8; ++st) {
    const int sw = st * 16 + rl;
#pragma unroll
    for (int r = 0; r < 4; ++r) {
      const float p = (lag[r] >= 0) ? S[st][r] * wgt[r] : 0.f;
      const int i = i0 + kq * 4 + r;
      const int gs = (sw >> 3) ^ (i & 7);
      P_lds[i * 128 + (gs << 3) + (sw & 7)] = (bf16_t)p;
      lag[r] -= 16;
      wgt[r] *= gi16;
    }
  }
  asm volatile("s_waitcnt lgkmcnt(0)" ::: "memory");
  __builtin_amdgcn_sched_barrier(0);

  // ---- PV: Y[i][e] = sum_sw P[i][sw] * V[sw][e] ----
  f32x4 Y[4] = {};
#pragma unroll
  for (int ks = 0; ks < 4; ++ks) {
    const int ia = i0 + rl;
    const int ga = (ks * 4 + kq) ^ (ia & 7);
    bf16x8 aF = *reinterpret_cast<const bf16x8*>(P_lds + ia * 128 + (ga << 3));
#pragma unroll
    for (int et = 0; et < 4; ++et) {
      const int e = et * 16 + rl;
      const int gb = (ks * 4 + kq) ^ (e & 7);
      bf16x8 bF = *reinterpret_cast<const bf16x8*>(VT_lds + e * 128 + (gb << 3));
      Y[et] = __builtin_amdgcn_mfma_f32_16x16x32_bf16(aF, bF, Y[et], 0, 0, 0);
    }
  }

  // ---- store y (f32) + fused GN partial stats ----
  float s = 0.f, ss = 0.f;
  const size_t ybase = (size_t)(b * TT + c * 64 + i0 + kq * 4) * DD + h * 64 + rl;
#pragma unroll
  for (int et = 0; et < 4; ++et)
#pragma unroll
    for (int r = 0; r < 4; ++r) {
      const float v = Y[et][r];
      s += v;
      ss += v * v;
      y[ybase + (size_t)r * DD + et * 16] = v;
    }
  s = waveSum(s);
  ss = waveSum(ss);
  if (lane == 0) { rs[w][0] = s; rs[w][1] = ss; }
  __syncthreads();
  if (tid == 0) {
    atomicAdd(&stats[bh * 2], rs[0][0] + rs[1][0] + rs[2][0] + rs[3][0]);
    atomicAdd(&stats[bh * 2 + 1], rs[0][1] + rs[1][1] + rs[2][1] + rs[3][1]);
  }
}

// ---------------- GroupNorm apply (finalize stats) * pre-sigmoided gate -> bf16 ----------------
__global__ __launch_bounds__(256) void gn_apply_kernel(const float* __restrict__ y,
                                                       const float* __restrict__ stats,
                                                       const bf16_t* __restrict__ gsig,
                                                       const float* __restrict__ gn_w,
                                                       const float* __restrict__ gn_b,
                                                       bf16_t* __restrict__ out) {
  const int row = blockIdx.x;
  const int tid = threadIdx.x;
  const int col = tid * 4;
  const int b = row >> 11;
  const int h = col >> 6;
  const float S = stats[(b * HH + h) * 2];
  const float SS = stats[(b * HH + h) * 2 + 1];
  const float inv = 1.0f / ((float)TT * 64.0f);
  const float mean = S * inv;
  const float var = SS * inv - mean * mean;
  const float rstd = rsqrtf(var + 1e-5f);
  float4 v = reinterpret_cast<const float4*>(y + (size_t)row * DD)[tid];
  float4 wv = reinterpret_cast<const float4*>(gn_w)[tid];
  float4 bv = reinterpret_cast<const float4*>(gn_b)[tid];
  bf16x4 gv = reinterpret_cast<const bf16x4*>(gsig + (size_t)row * DD)[tid];
  bf16x4 o;
  o[0] = (bf16_t)((((v.x - mean) * rstd) * wv.x + bv.x) * (float)gv[0]);
  o[1] = (bf16_t)((((v.y - mean) * rstd) * wv.y + bv.y) * (float)gv[1]);
  o[2] = (bf16_t)((((v.z - mean) * rstd) * wv.z + bv.z) * (float)gv[2]);
  o[3] = (bf16_t)((((v.w - mean) * rstd) * wv.w + bv.w) * (float)gv[3]);
  reinterpret_cast<bf16x4*>(out + (size_t)row * DD)[tid] = o;
}

extern "C" void kernel_launch(void* const* d_in, const int* in_sizes, int n_in,
                              void* d_out, int out_size, void* d_ws, size_t ws_size,
                              hipStream_t stream) {
  const float* x = (const float*)d_in[0];
  const float* ln1_w = (const float*)d_in[1];
  const float* ln2_w = (const float*)d_in[2];
  const float* Wq = (const float*)d_in[3];
  const float* Wk = (const float*)d_in[4];
  const float* Wv = (const float*)d_in[5];
  const float* Wg = (const float*)d_in[6];
  const float* Wo = (const float*)d_in[7];
  const float* gamma = (const float*)d_in[8];
  const float* gn_w = (const float*)d_in[9];
  const float* gn_b = (const float*)d_in[10];
  const float* gate_w = (const float*)d_in[11];
  const float* up_w = (const float*)d_in[12];
  const float* down_w = (const float*)d_in[13];
  float* out = (float*)d_out;

  const int M = 2 * TT;  // 4096

  char* ws = (char*)d_ws;
  size_t off = 0;
  auto alloc = [&](size_t bytes) -> void* {
    void* p = ws + off;
    off += (bytes + 255) & ~(size_t)255;
    return p;
  };
  bf16_t* h_bf = (bf16_t*)alloc((size_t)M * DD * 2);
  bf16_t* Wqkvg_bf = (bf16_t*)alloc((size_t)4 * DD * DD * 2);
  bf16_t* Wo_bf = (bf16_t*)alloc((size_t)DD * DD * 2);
  bf16_t* GU_bf = (bf16_t*)alloc((size_t)2 * II * DD * 2);
  bf16_t* down_bf = (bf16_t*)alloc((size_t)DD * II * 2);
  bf16_t* qkv_bf = (bf16_t*)alloc((size_t)M * 3 * DD * 2);
  bf16_t* gsig = (bf16_t*)alloc((size_t)M * DD * 2);
  float* yBuf = (float*)alloc((size_t)M * DD * 4);
  bf16_t* ygated = (bf16_t*)alloc((size_t)M * DD * 2);
  bf16_t* act = (bf16_t*)alloc((size_t)M * II * 2);
  float* stats = (float*)alloc(64 * 4);
  (void)ws_size; (void)in_sizes; (void)n_in; (void)out_size;

  float* x2 = yBuf;

  // fused weight prep (+ stats zeroing)
  prep_kernel<<<13568, 256, 0, stream>>>(Wq, Wk, Wv, Wg, Wo, gate_w, up_w, down_w,
                                         Wqkvg_bf, Wo_bf, GU_bf, down_bf, stats);

  // h = rmsnorm(x) -> bf16
  rmsnorm_kernel<<<M, 256, 0, stream>>>(x, ln1_w, h_bf);

  // qkv (bf16) + sigmoid(g) (bf16) = h @ [Wq;Wk;Wv;Wg]^T
  {
    dim3 g(4 * DD / 256, M / 128);  // 16 x 32 = 512 blocks = 2/CU
    gemm128x256<3><<<g, 512, 73728, stream>>>(h_bf, Wqkvg_bf, qkv_bf, gsig, M, 4 * DD, DD);
  }

  // windowed decay scan (MFMA) -> y (f32) + partial GN stats
  {
    dim3 g(TT / 64, 2 * HH);
    retscan_mfma<<<g, 256, 0, stream>>>(qkv_bf, gamma, yBuf, stats);
  }

  // GN apply * sigmoid(g)
  gn_apply_kernel<<<M, 256, 0, stream>>>(yBuf, stats, gsig, gn_w, gn_b, ygated);

  // x2 = x + ygated @ Wo^T   (overwrites yBuf; gn_apply already consumed it)
  {
    dim3 g(DD / 128, M / 64);  // 8 x 64 = 512 blocks
    gemm64x128<<<g, 256, 0, stream>>>(ygated, Wo_bf, x2, x, M, DD, DD);
  }

  // h2 = rmsnorm(x2) -> bf16
  rmsnorm_kernel<<<M, 256, 0, stream>>>(x2, ln2_w, h_bf);

  // act = silu(h2 @ gate^T) * (h2 @ up^T) -> bf16, fused epilogue
  {
    dim3 g(2 * II / 256, M / 128);  // 22 x 32 = 704 blocks
    gemm128x256<2><<<g, 512, 73728, stream>>>(h_bf, GU_bf, act, nullptr, M, 2 * II, DD);
  }

  // out = x2 + act @ down^T
  {
    dim3 g(DD / 128, M / 64);  // 512 blocks
    gemm64x128<<<g, 256, 0, stream>>>(act, down_bf, out, x2, M, DD, II);
  }
}

// Round 15
// 219.531 us; speedup vs baseline: 1.4256x; 1.0149x over previous
//
#include <hip/hip_runtime.h>
#include <hip/hip_bf16.h>
#include <cstdint>
#include <cstddef>

typedef __bf16 bf16_t;
typedef __bf16 bf16x4 __attribute__((ext_vector_type(4)));
typedef __bf16 bf16x8 __attribute__((ext_vector_type(8)));
typedef float f32x4 __attribute__((ext_vector_type(4)));

#define DEVINL __device__ __forceinline__

// B=2, T=2048, D=1024, H=16, d=64, I=2816
#define TT 2048
#define DD 1024
#define HH 16
#define II 2816

DEVINL float waveSum(float v) {
#pragma unroll
  for (int m = 32; m >= 1; m >>= 1) v += __shfl_xor(v, m, 64);
  return v;
}

DEVINL float sigmoidf_(float z) { return 1.0f / (1.0f + __expf(-z)); }

DEVINL void gload_lds16(const bf16_t* g, bf16_t* l) {
  __builtin_amdgcn_global_load_lds((const __attribute__((address_space(1))) void*)g,
                                   (__attribute__((address_space(3))) void*)l, 16, 0, 0);
}

// ---------------- fused weight prep: cvt 5x DxD, pack GU interleaved, cvt down, zero stats ----
__global__ __launch_bounds__(256) void prep_kernel(const float* __restrict__ Wq,
                                                   const float* __restrict__ Wk,
                                                   const float* __restrict__ Wv,
                                                   const float* __restrict__ Wg,
                                                   const float* __restrict__ Wo,
                                                   const float* __restrict__ gate_w,
                                                   const float* __restrict__ up_w,
                                                   const float* __restrict__ down_w,
                                                   bf16_t* __restrict__ Wqkvg_bf,
                                                   bf16_t* __restrict__ Wo_bf,
                                                   bf16_t* __restrict__ GU_bf,
                                                   bf16_t* __restrict__ down_bf,
                                                   float* __restrict__ stats) {
  const int bid = blockIdx.x;
  const int tid = threadIdx.x;
  if (bid == 0 && tid < 64) stats[tid] = 0.f;
  if (bid < 5120) {
    const int which = bid >> 10;
    const float* src;
    bf16_t* dst;
    switch (which) {
      case 0: src = Wq; dst = Wqkvg_bf; break;
      case 1: src = Wk; dst = Wqkvg_bf + (size_t)DD * DD; break;
      case 2: src = Wv; dst = Wqkvg_bf + 2 * (size_t)DD * DD; break;
      case 3: src = Wg; dst = Wqkvg_bf + 3 * (size_t)DD * DD; break;
      default: src = Wo; dst = Wo_bf; break;
    }
    const int i = (bid & 1023) * 256 + tid;
    float4 v = reinterpret_cast<const float4*>(src)[i];
    bf16x4 o;
    o[0] = (bf16_t)v.x; o[1] = (bf16_t)v.y; o[2] = (bf16_t)v.z; o[3] = (bf16_t)v.w;
    reinterpret_cast<bf16x4*>(dst)[i] = o;
  } else if (bid < 10752) {
    // GU pack: dst row r: jb=r/32, s=r%32; s<16 -> gate row 16*jb+s ; else up
    const int r = bid - 5120;
    const int jb = r >> 5, s = r & 31;
    const float* src = (s < 16) ? (gate_w + (size_t)(jb * 16 + s) * DD)
                                : (up_w + (size_t)(jb * 16 + s - 16) * DD);
    float4 v = reinterpret_cast<const float4*>(src)[tid];
    bf16x4 o;
    o[0] = (bf16_t)v.x; o[1] = (bf16_t)v.y; o[2] = (bf16_t)v.z; o[3] = (bf16_t)v.w;
    reinterpret_cast<bf16x4*>(GU_bf + (size_t)r * DD)[tid] = o;
  } else {
    const int i = (bid - 10752) * 256 + tid;
    float4 v = reinterpret_cast<const float4*>(down_w)[i];
    bf16x4 o;
    o[0] = (bf16_t)v.x; o[1] = (bf16_t)v.y; o[2] = (bf16_t)v.z; o[3] = (bf16_t)v.w;
    reinterpret_cast<bf16x4*>(down_bf)[i] = o;
  }
}

// ---------------- RMSNorm (row of 1024) -> bf16 ----------------
__global__ __launch_bounds__(256) void rmsnorm_kernel(const float* __restrict__ x,
                                                      const float* __restrict__ w,
                                                      bf16_t* __restrict__ out) {
  const int row = blockIdx.x;
  const int tid = threadIdx.x;
  const float4 v = reinterpret_cast<const float4*>(x + (size_t)row * DD)[tid];
  float ss = v.x * v.x + v.y * v.y + v.z * v.z + v.w * v.w;
  ss = waveSum(ss);
  __shared__ float red[4];
  if ((tid & 63) == 0) red[tid >> 6] = ss;
  __syncthreads();
  const float total = red[0] + red[1] + red[2] + red[3];
  const float rstd = rsqrtf(total * (1.0f / (float)DD) + 1e-6f);
  const float4 wv = reinterpret_cast<const float4*>(w)[tid];
  bf16x4 o;
  o[0] = (bf16_t)(v.x * rstd * wv.x);
  o[1] = (bf16_t)(v.y * rstd * wv.y);
  o[2] = (bf16_t)(v.z * rstd * wv.z);
  o[3] = (bf16_t)(v.w * rstd * wv.w);
  reinterpret_cast<bf16x4*>(out + (size_t)row * DD)[tid] = o;
}

// ============ 128x256 8-wave BK=32 ring-3 GEMM (B^T input), 2 blocks/CU ============
// C[m,n] = sum_k A[m,k]*B[n,k].  M == 4096 (gridDim.y == 32), N%256==0, K%32==0, K>=96.
// XCD chunking + col-major-within-chunk decode: XCD x owns 4 A-row-bands (1MB, L2-hot)
// and streams each B panel ONCE (hot across the 4-row microgroup).
// EPI: 2 = silu-fused bf16 (gate/up interleaved pairs, out stride II)
//      3 = qkv/g split bf16 (col<3072 -> O1 stride 3072; else sigmoid -> O2 stride DD)
template <int EPI>
__global__ __launch_bounds__(512, 4) void gemm128x256(const bf16_t* __restrict__ A,
                                                      const bf16_t* __restrict__ B,
                                                      bf16_t* __restrict__ O1,
                                                      bf16_t* __restrict__ O2,
                                                      int M, int N, int K) {
  extern __shared__ __align__(16) char lds[];
  const int tid = threadIdx.x;
  const int wid = tid >> 6;   // 0..7
  const int lane = tid & 63;
  const int wr = wid >> 2;    // 0..1  M-halves of 64
  const int wc = wid & 3;     // 0..3  N-quarters of 64

  // XCD chunk transform (nwg % 8 == 0; chunk = nwg/8 = 4*gx since gridDim.y == 32)
  const int gx = gridDim.x;
  const int nwg = gx * gridDim.y;
  int flat = blockIdx.y * gx + blockIdx.x;
  flat = (flat & 7) * (nwg >> 3) + (flat >> 3);
  // col-major-within-chunk: 4-row microgroups; B panel visited once per XCD
  const int rowgroup = flat / (gx * 4);        // == XCD id
  const int rem = flat - rowgroup * gx * 4;
  const int col0 = (rem >> 2) * 256;
  const int row0 = (rowgroup * 4 + (rem & 3)) * 128;

  const int ls_row = lane >> 2;
  const int ls_col = ((lane & 3) ^ ((lane >> 3) & 3)) * 8;
  const bf16_t* gA = A + (size_t)(row0 + wid * 16 + ls_row) * K + ls_col;
  const bf16_t* gB = B + (size_t)(col0 + wid * 32 + ls_row) * K + ls_col;

  const int kq = lane >> 4;
  const int rl = lane & 15;
  const int xg = (rl >> 1) & 3;
  const int gsel = (kq ^ xg) << 4;  // byte offset of the lane's 16B granule

  f32x4 acc[4][4] = {};
  const int nt = K >> 5;  // >= 3

  auto stage = [&](int t) {
    char* slot = lds + (t % 3) * 24576;
    const int ko = t << 5;
    gload_lds16(gA + ko, (bf16_t*)(slot + wid * 1024));               // A: 128x32
#pragma unroll
    for (int j = 0; j < 2; ++j)                                       // B: 256x32
      gload_lds16(gB + (size_t)j * 16 * K + ko,
                  (bf16_t*)(slot + 8192 + wid * 2048 + j * 1024));
  };

  // prologue: stage tiles 0,1 ; wait tile 0 (3 = tile 1 remains in flight)
  stage(0); stage(1);
  asm volatile("s_waitcnt vmcnt(3)" ::: "memory");
  __builtin_amdgcn_s_barrier();
  __builtin_amdgcn_sched_barrier(0);

  for (int t = 0; t < nt; ++t) {
    if (t + 2 < nt) stage(t + 2);  // slot (t+2)%3 == (t-1)%3, read finished at t-1 barrier
    const char* ab = lds + (t % 3) * 24576;
    const char* bb = ab + 8192;
    bf16x8 aF[4], bF[4];
#pragma unroll
    for (int n = 0; n < 4; ++n)
      bF[n] = *reinterpret_cast<const bf16x8*>(bb + (wc * 64 + n * 16 + rl) * 64 + gsel);
#pragma unroll
    for (int m = 0; m < 4; ++m)
      aF[m] = *reinterpret_cast<const bf16x8*>(ab + (wr * 64 + m * 16 + rl) * 64 + gsel);
    __builtin_amdgcn_s_setprio(1);
#pragma unroll
    for (int m = 0; m < 4; ++m)
#pragma unroll
      for (int n = 0; n < 4; ++n)
        acc[m][n] = __builtin_amdgcn_mfma_f32_16x16x32_bf16(aF[m], bF[n], acc[m][n], 0, 0, 0);
    __builtin_amdgcn_s_setprio(0);
    if (t + 2 < nt) {
      asm volatile("s_waitcnt vmcnt(3)" ::: "memory");
    } else if (t + 2 == nt) {
      asm volatile("s_waitcnt vmcnt(0)" ::: "memory");
    }
    __builtin_amdgcn_s_barrier();
    __builtin_amdgcn_sched_barrier(0);
  }

  // ---- epilogue ----
  const int crow = row0 + wr * 64 + kq * 4;
  const int ccol = col0 + wc * 64 + rl;
  if (EPI == 2) {
    const int obase = (col0 + wc * 64) / 2 + rl;
#pragma unroll
    for (int m = 0; m < 4; ++m)
#pragma unroll
      for (int p = 0; p < 2; ++p)
#pragma unroll
        for (int r = 0; r < 4; ++r) {
          const float g = acc[m][2 * p][r];
          const float u = acc[m][2 * p + 1][r];
          O1[(size_t)(crow + m * 16 + r) * II + (obase + p * 16)] =
              (bf16_t)(g * sigmoidf_(g) * u);
        }
  } else {  // EPI == 3
    if (col0 < 3072) {
#pragma unroll
      for (int m = 0; m < 4; ++m)
#pragma unroll
        for (int n = 0; n < 4; ++n)
#pragma unroll
          for (int r = 0; r < 4; ++r)
            O1[(size_t)(crow + m * 16 + r) * 3072 + (ccol + n * 16)] = (bf16_t)acc[m][n][r];
    } else {
#pragma unroll
      for (int m = 0; m < 4; ++m)
#pragma unroll
        for (int n = 0; n < 4; ++n)
#pragma unroll
          for (int r = 0; r < 4; ++r)
            O2[(size_t)(crow + m * 16 + r) * DD + (ccol + n * 16 - 3072)] =
                (bf16_t)sigmoidf_(acc[m][n][r]);
    }
  }
}

// -------- 64x128 4-wave BK=32 ring-5 GEMM (N=1024: Wo, down), C = acc + addsrc --------
// Grid MUST be (8, 64). Block remap: d=by*8+bx -> col=d>>6, row=d&63 pins A-band r to
// XCD r%8 (per-XCD A working set 2.9MB fits L2; A fetched ~once chip-wide).
// Ring-5 LDS (30KB), depth-4 prefetch, counted vmcnt(9/6/3/0).
__global__ __launch_bounds__(256) void gemm64x128(const bf16_t* __restrict__ A,
                                                  const bf16_t* __restrict__ B,
                                                  float* __restrict__ C,
                                                  const float* __restrict__ addsrc,
                                                  int M, int N, int K) {
  __shared__ __align__(16) bf16_t sm[5 * 6144];  // slot = A 64x32 (2048) + B 128x32 (4096)
  const int tid = threadIdx.x;
  const int wid = tid >> 6;  // 0..3
  const int lane = tid & 63;
  const int d = blockIdx.y * 8 + blockIdx.x;
  const int row0 = (d & 63) * 64;
  const int col0 = (d >> 6) * 128;

  f32x4 acc[4][2] = {};

  const int ls_row = lane >> 2;
  const int ls_col = ((lane & 3) ^ ((lane >> 3) & 3)) * 8;  // inverse-swizzled source
  const bf16_t* gA = A + (size_t)(row0 + wid * 16 + ls_row) * K + ls_col;
  const bf16_t* gB = B + (size_t)(col0 + wid * 32 + ls_row) * K + ls_col;

  const int rl = lane & 15;
  const int kq = lane >> 4;
  const int xg = (rl >> 1) & 3;
  const int ge = (kq ^ xg) * 8;  // element offset of the lane's granule

  const int nt = K >> 5;  // 32 (Wo) or 88 (down); >= 5
  auto stage = [&](int t) {
    bf16_t* slot = sm + (t % 5) * 6144;
    const int ko = t << 5;
    gload_lds16(gA + ko, slot + wid * 512);                     // A: 1 issue/wave
#pragma unroll
    for (int j = 0; j < 2; ++j)                                 // B: 2 issues/wave
      gload_lds16(gB + (size_t)j * 16 * K + ko, slot + 2048 + wid * 1024 + j * 512);
  };

  // prologue: stage tiles 0..3 (12 loads); vmcnt(9) -> tile 0 landed, 3 tiles in flight
  stage(0); stage(1); stage(2); stage(3);
  asm volatile("s_waitcnt vmcnt(9)" ::: "memory");
  __builtin_amdgcn_s_barrier();
  __builtin_amdgcn_sched_barrier(0);

  for (int t = 0; t < nt; ++t) {
    if (t + 5 <= nt) stage(t + 4);  // slot (t+4)%5 == (t-1)%5: reads retired at t-1 barrier
    const bf16_t* slot = sm + (t % 5) * 6144;
    bf16x8 aF[4], bF[2];
#pragma unroll
    for (int m = 0; m < 4; ++m)
      aF[m] = *reinterpret_cast<const bf16x8*>(slot + (m * 16 + rl) * 32 + ge);
#pragma unroll
    for (int n = 0; n < 2; ++n)
      bF[n] = *reinterpret_cast<const bf16x8*>(slot + 2048 + (wid * 32 + n * 16 + rl) * 32 + ge);
    __builtin_amdgcn_s_setprio(1);
#pragma unroll
    for (int m = 0; m < 4; ++m)
#pragma unroll
      for (int n = 0; n < 2; ++n)
        acc[m][n] = __builtin_amdgcn_mfma_f32_16x16x32_bf16(aF[m], bF[n], acc[m][n], 0, 0, 0);
    __builtin_amdgcn_s_setprio(0);
    // counted drain: ensure tile t+1 landed; keep later tiles in flight
    if (t + 5 <= nt) {
      asm volatile("s_waitcnt vmcnt(9)" ::: "memory");
    } else if (t + 4 == nt) {
      asm volatile("s_waitcnt vmcnt(6)" ::: "memory");
    } else if (t + 3 == nt) {
      asm volatile("s_waitcnt vmcnt(3)" ::: "memory");
    } else if (t + 2 == nt) {
      asm volatile("s_waitcnt vmcnt(0)" ::: "memory");
    }
    __builtin_amdgcn_s_barrier();
    __builtin_amdgcn_sched_barrier(0);
  }

  const int ccol = col0 + wid * 32 + rl;
#pragma unroll
  for (int m = 0; m < 4; ++m)
#pragma unroll
    for (int n = 0; n < 2; ++n)
#pragma unroll
      for (int r = 0; r < 4; ++r) {
        const size_t idx = (size_t)(row0 + m * 16 + kq * 4 + r) * N + (ccol + n * 16);
        C[idx] = acc[m][n][r] + addsrc[idx];
      }
}

// ---------------- RetNet windowed decay scan on MFMA + fused GN partial stats ----------------
__global__ __launch_bounds__(256) void retscan_mfma(const bf16_t* __restrict__ qkv,
                                                    const float* __restrict__ gamma,
                                                    float* __restrict__ y,
                                                    float* __restrict__ stats) {
  const int c = blockIdx.x;
  const int bh = blockIdx.y;
  const int b = bh >> 4;
  const int h = bh & 15;
  const int tid = threadIdx.x;
  const int w = tid >> 6;
  const int lane = tid & 63;
  const int kq = lane >> 4;
  const int rl = lane & 15;

  __shared__ __align__(16) bf16_t K_lds[128 * 64];    // [sw][j]   swizzled
  __shared__ __align__(16) bf16_t VT_lds[64 * 128];   // [e][sw]   swizzled
  __shared__ __align__(16) bf16_t P_lds[64 * 128];    // [i][sw]   swizzled
  __shared__ float rs[4][2];

  const size_t rstr = 3 * DD;
  const bf16_t* base = qkv + (size_t)(b * TT) * rstr + h * 64;  // Q
  const bf16_t* kgl = base + DD;
  const bf16_t* vgl = base + 2 * DD;

  // ---- stage K (swizzled) and V^T (transposed, swizzled) ----
  for (int g = tid; g < 1024; g += 256) {
    const int sw = g >> 3, gr = g & 7;
    const int t = c * 64 - 64 + sw;
    bf16x8 kv = {};
    bf16x8 vv = {};
    if (t >= 0) {
      kv = *reinterpret_cast<const bf16x8*>(kgl + (size_t)t * rstr + gr * 8);
      vv = *reinterpret_cast<const bf16x8*>(vgl + (size_t)t * rstr + gr * 8);
    }
    *reinterpret_cast<bf16x8*>(K_lds + sw * 64 + ((gr ^ (sw & 7)) << 3)) = kv;
#pragma unroll
    for (int j = 0; j < 8; ++j) {
      const int e = gr * 8 + j;
      const int gs = (sw >> 3) ^ (e & 7);
      VT_lds[e * 128 + (gs << 3) + (sw & 7)] = vv[j];
    }
  }

  // ---- Q fragments (direct from global; rows i0..i0+15 of this wave) ----
  const int i0 = w * 16;
  const bf16_t* qrow = base + (size_t)(c * 64 + i0 + rl) * rstr;
  bf16x8 qF0 = *reinterpret_cast<const bf16x8*>(qrow + kq * 8);
  bf16x8 qF1 = *reinterpret_cast<const bf16x8*>(qrow + 32 + kq * 8);
  const float gam = sigmoidf_(gamma[h]);
  const float l2g = __log2f(gam);
  const float gi16 = exp2f(-16.f * l2g);  // gam^-16: lag decreases by 16 per sw-tile

  __syncthreads();

  // ---- QK^T: S[i=i0+kq*4+r][sw=st*16+rl] ----
  f32x4 S[8];
#pragma unroll
  for (int st = 0; st < 8; ++st) {
    const int sw = st * 16 + rl;
    const bf16_t* krow = K_lds + sw * 64;
    bf16x8 kF0 = *reinterpret_cast<const bf16x8*>(krow + ((kq ^ (sw & 7)) << 3));
    bf16x8 kF1 = *reinterpret_cast<const bf16x8*>(krow + (((4 + kq) ^ (sw & 7)) << 3));
    f32x4 s = {};
    s = __builtin_amdgcn_mfma_f32_16x16x32_bf16(qF0, kF0, s, 0, 0, 0);
    s = __builtin_amdgcn_mfma_f32_16x16x32_bf16(qF1, kF1, s, 0, 0, 0);
    S[st] = s;
  }

  // ---- decay * mask -> bf16 P (own rows only) ----
  float wgt[4];
  int lag[4];
#pragma unroll
  for (int r = 0; r < 4; ++r) {
    lag[r] = 64 + i0 + kq * 4 + r - rl;  // at st=0; always >=0 here
    wgt[r] = exp2f((float)lag[r] * l2g);
  }
#pragma unroll
  for (int st = 0; st < 8; ++st) {
    const int sw = st * 16 + rl;
#pragma unroll
    for (int r = 0; r < 4; ++r) {
      const float p = (lag[r] >= 0) ? S[st][r] * wgt[r] : 0.f;
      const int i = i0 + kq * 4 + r;
      const int gs = (sw >> 3) ^ (i & 7);
      P_lds[i * 128 + (gs << 3) + (sw & 7)] = (bf16_t)p;
      lag[r] -= 16;
      wgt[r] *= gi16;
    }
  }
  asm volatile("s_waitcnt lgkmcnt(0)" ::: "memory");
  __builtin_amdgcn_sched_barrier(0);

  // ---- PV: Y[i][e] = sum_sw P[i][sw] * V[sw][e] ----
  f32x4 Y[4] = {};
#pragma unroll
  for (int ks = 0; ks < 4; ++ks) {
    const int ia = i0 + rl;
    const int ga = (ks * 4 + kq) ^ (ia & 7);
    bf16x8 aF = *reinterpret_cast<const bf16x8*>(P_lds + ia * 128 + (ga << 3));
#pragma unroll
    for (int et = 0; et < 4; ++et) {
      const int e = et * 16 + rl;
      const int gb = (ks * 4 + kq) ^ (e & 7);
      bf16x8 bF = *reinterpret_cast<const bf16x8*>(VT_lds + e * 128 + (gb << 3));
      Y[et] = __builtin_amdgcn_mfma_f32_16x16x32_bf16(aF, bF, Y[et], 0, 0, 0);
    }
  }

  // ---- store y (f32) + fused GN partial stats ----
  float s = 0.f, ss = 0.f;
  const size_t ybase = (size_t)(b * TT + c * 64 + i0 + kq * 4) * DD + h * 64 + rl;
#pragma unroll
  for (int et = 0; et < 4; ++et)
#pragma unroll
    for (int r = 0; r < 4; ++r) {
      const float v = Y[et][r];
      s += v;
      ss += v * v;
      y[ybase + (size_t)r * DD + et * 16] = v;
    }
  s = waveSum(s);
  ss = waveSum(ss);
  if (lane == 0) { rs[w][0] = s; rs[w][1] = ss; }
  __syncthreads();
  if (tid == 0) {
    atomicAdd(&stats[bh * 2], rs[0][0] + rs[1][0] + rs[2][0] + rs[3][0]);
    atomicAdd(&stats[bh * 2 + 1], rs[0][1] + rs[1][1] + rs[2][1] + rs[3][1]);
  }
}

// ---------------- GroupNorm apply (finalize stats) * pre-sigmoided gate -> bf16 ----------------
__global__ __launch_bounds__(256) void gn_apply_kernel(const float* __restrict__ y,
                                                       const float* __restrict__ stats,
                                                       const bf16_t* __restrict__ gsig,
                                                       const float* __restrict__ gn_w,
                                                       const float* __restrict__ gn_b,
                                                       bf16_t* __restrict__ out) {
  const int row = blockIdx.x;
  const int tid = threadIdx.x;
  const int col = tid * 4;
  const int b = row >> 11;
  const int h = col >> 6;
  const float S = stats[(b * HH + h) * 2];
  const float SS = stats[(b * HH + h) * 2 + 1];
  const float inv = 1.0f / ((float)TT * 64.0f);
  const float mean = S * inv;
  const float var = SS * inv - mean * mean;
  const float rstd = rsqrtf(var + 1e-5f);
  float4 v = reinterpret_cast<const float4*>(y + (size_t)row * DD)[tid];
  float4 wv = reinterpret_cast<const float4*>(gn_w)[tid];
  float4 bv = reinterpret_cast<const float4*>(gn_b)[tid];
  bf16x4 gv = reinterpret_cast<const bf16x4*>(gsig + (size_t)row * DD)[tid];
  bf16x4 o;
  o[0] = (bf16_t)((((v.x - mean) * rstd) * wv.x + bv.x) * (float)gv[0]);
  o[1] = (bf16_t)((((v.y - mean) * rstd) * wv.y + bv.y) * (float)gv[1]);
  o[2] = (bf16_t)((((v.z - mean) * rstd) * wv.z + bv.z) * (float)gv[2]);
  o[3] = (bf16_t)((((v.w - mean) * rstd) * wv.w + bv.w) * (float)gv[3]);
  reinterpret_cast<bf16x4*>(out + (size_t)row * DD)[tid] = o;
}

extern "C" void kernel_launch(void* const* d_in, const int* in_sizes, int n_in,
                              void* d_out, int out_size, void* d_ws, size_t ws_size,
                              hipStream_t stream) {
  const float* x = (const float*)d_in[0];
  const float* ln1_w = (const float*)d_in[1];
  const float* ln2_w = (const float*)d_in[2];
  const float* Wq = (const float*)d_in[3];
  const float* Wk = (const float*)d_in[4];
  const float* Wv = (const float*)d_in[5];
  const float* Wg = (const float*)d_in[6];
  const float* Wo = (const float*)d_in[7];
  const float* gamma = (const float*)d_in[8];
  const float* gn_w = (const float*)d_in[9];
  const float* gn_b = (const float*)d_in[10];
  const float* gate_w = (const float*)d_in[11];
  const float* up_w = (const float*)d_in[12];
  const float* down_w = (const float*)d_in[13];
  float* out = (float*)d_out;

  const int M = 2 * TT;  // 4096

  char* ws = (char*)d_ws;
  size_t off = 0;
  auto alloc = [&](size_t bytes) -> void* {
    void* p = ws + off;
    off += (bytes + 255) & ~(size_t)255;
    return p;
  };
  bf16_t* h_bf = (bf16_t*)alloc((size_t)M * DD * 2);
  bf16_t* Wqkvg_bf = (bf16_t*)alloc((size_t)4 * DD * DD * 2);
  bf16_t* Wo_bf = (bf16_t*)alloc((size_t)DD * DD * 2);
  bf16_t* GU_bf = (bf16_t*)alloc((size_t)2 * II * DD * 2);
  bf16_t* down_bf = (bf16_t*)alloc((size_t)DD * II * 2);
  bf16_t* qkv_bf = (bf16_t*)alloc((size_t)M * 3 * DD * 2);
  bf16_t* gsig = (bf16_t*)alloc((size_t)M * DD * 2);
  float* yBuf = (float*)alloc((size_t)M * DD * 4);
  bf16_t* ygated = (bf16_t*)alloc((size_t)M * DD * 2);
  bf16_t* act = (bf16_t*)alloc((size_t)M * II * 2);
  float* stats = (float*)alloc(64 * 4);
  (void)ws_size; (void)in_sizes; (void)n_in; (void)out_size;

  float* x2 = yBuf;

  // fused weight prep (+ stats zeroing)
  prep_kernel<<<13568, 256, 0, stream>>>(Wq, Wk, Wv, Wg, Wo, gate_w, up_w, down_w,
                                         Wqkvg_bf, Wo_bf, GU_bf, down_bf, stats);

  // h = rmsnorm(x) -> bf16
  rmsnorm_kernel<<<M, 256, 0, stream>>>(x, ln1_w, h_bf);

  // qkv (bf16) + sigmoid(g) (bf16) = h @ [Wq;Wk;Wv;Wg]^T
  {
    dim3 g(4 * DD / 256, M / 128);  // 16 x 32 = 512 blocks = 2/CU
    gemm128x256<3><<<g, 512, 73728, stream>>>(h_bf, Wqkvg_bf, qkv_bf, gsig, M, 4 * DD, DD);
  }

  // windowed decay scan (MFMA) -> y (f32) + partial GN stats
  {
    dim3 g(TT / 64, 2 * HH);
    retscan_mfma<<<g, 256, 0, stream>>>(qkv_bf, gamma, yBuf, stats);
  }

  // GN apply * sigmoid(g)
  gn_apply_kernel<<<M, 256, 0, stream>>>(yBuf, stats, gsig, gn_w, gn_b, ygated);

  // x2 = x + ygated @ Wo^T   (overwrites yBuf; gn_apply already consumed it)
  {
    dim3 g(DD / 128, M / 64);  // 8 x 64 = 512 blocks
    gemm64x128<<<g, 256, 0, stream>>>(ygated, Wo_bf, x2, x, M, DD, DD);
  }

  // h2 = rmsnorm(x2) -> bf16
  rmsnorm_kernel<<<M, 256, 0, stream>>>(x2, ln2_w, h_bf);

  // act = silu(h2 @ gate^T) * (h2 @ up^T) -> bf16, fused epilogue
  {
    dim3 g(2 * II / 256, M / 128);  // 22 x 32 = 704 blocks
    gemm128x256<2><<<g, 512, 73728, stream>>>(h_bf, GU_bf, act, nullptr, M, 2 * II, DD);
  }

  // out = x2 + act @ down^T
  {
    dim3 g(DD / 128, M / 64);  // 512 blocks
    gemm64x128<<<g, 256, 0, stream>>>(act, down_bf, out, x2, M, DD, II);
  }
}